// Round 4
// baseline (189.978 us; speedup 1.0000x reference)
//
#include <hip/hip_runtime.h>
#include <hip/hip_bf16.h>

// ---------- types / helpers ----------
typedef __attribute__((ext_vector_type(8))) short bf16x8;   // 8 bf16 = 4 VGPRs
typedef __attribute__((ext_vector_type(4))) short bf16x4;
typedef __attribute__((ext_vector_type(4))) float f32x4;

__device__ __forceinline__ short f2bf(float f) {
    unsigned u = __float_as_uint(f);
    u += 0x7fff + ((u >> 16) & 1);          // round-to-nearest-even
    return (short)(u >> 16);
}
__device__ __forceinline__ float bf2f(short s) {
    return __uint_as_float(((unsigned)(unsigned short)s) << 16);
}
__device__ __forceinline__ unsigned pk_bf16(float lo, float hi) {
    __hip_bfloat162 t = __float22bfloat162_rn(make_float2(lo, hi));
    unsigned u;
    __builtin_memcpy(&u, &t, 4);
    return u;
}

#define GLOAD_LDS16(gp, lp)                                                            \
    __builtin_amdgcn_global_load_lds(                                                  \
        (const __attribute__((address_space(1))) unsigned*)(gp),                       \
        (__attribute__((address_space(3))) unsigned*)(lp), 16, 0, 0)

#define QK_SCALE 0.180336879f   // (1/sqrt(64)) * log2(e), folded into q at GEMM1
#define MFMA16(a, b, c) __builtin_amdgcn_mfma_f32_16x16x32_bf16((a), (b), (c), 0, 0, 0)

// ---------- fused prep: enc->bf16, biases->bf16, Wa/Wo -> transposed bf16 ----------
__device__ __forceinline__ void tcvt_tile(const float* __restrict__ W, short* __restrict__ Wt,
                                          int K, int N, int bx, int by, int t,
                                          short (*tile)[72]) {
    const int k0 = by * 64, n0 = bx * 64;
    #pragma unroll
    for (int jj = 0; jj < 4; ++jj) {
        int row = jj * 16 + (t >> 4);
        int col = (t & 15) * 4;
        f32x4 v = *(const f32x4*)&W[(size_t)(k0 + row) * N + n0 + col];
        bf16x4 b = {f2bf(v.x), f2bf(v.y), f2bf(v.z), f2bf(v.w)};
        *(bf16x4*)&tile[row][col] = b;
    }
    __syncthreads();
    const int nr = t >> 2, kc = (t & 3) * 16;
    bf16x8 o0, o1;
    #pragma unroll
    for (int j = 0; j < 8; ++j) { o0[j] = tile[kc + j][nr]; o1[j] = tile[kc + 8 + j][nr]; }
    short* dst = &Wt[(size_t)(n0 + nr) * K + k0 + kc];
    *(bf16x8*)dst = o0;
    *(bf16x8*)(dst + 8) = o1;
}

__global__ __launch_bounds__(256) void prep_kernel(
    const float* __restrict__ enc, const float* __restrict__ Wa,
    const float* __restrict__ ba, const float* __restrict__ Wo,
    const float* __restrict__ bo, short* __restrict__ Abf,
    short* __restrict__ WtA, short* __restrict__ bbA,
    short* __restrict__ WtO, short* __restrict__ bbO)
{
    __shared__ alignas(16) short tile[64][72];
    const int id = blockIdx.x, t = threadIdx.x;
    if (id < 2048) {
        const int i = id * 2048 + t * 8;
        f32x4 a = *(const f32x4*)&enc[i];
        f32x4 b = *(const f32x4*)&enc[i + 4];
        bf16x8 o = {f2bf(a.x), f2bf(a.y), f2bf(a.z), f2bf(a.w),
                    f2bf(b.x), f2bf(b.y), f2bf(b.z), f2bf(b.w)};
        *(bf16x8*)&Abf[i] = o;
    } else if (id == 2048) {
        for (int j = t * 8; j < 3072; j += 2048) {
            f32x4 a = *(const f32x4*)&ba[j];
            f32x4 b = *(const f32x4*)&ba[j + 4];
            bf16x8 o = {f2bf(a.x), f2bf(a.y), f2bf(a.z), f2bf(a.w),
                        f2bf(b.x), f2bf(b.y), f2bf(b.z), f2bf(b.w)};
            *(bf16x8*)&bbA[j] = o;
        }
    } else if (id == 2049) {
        if (t < 128) {
            const int j = t * 8;
            f32x4 a = *(const f32x4*)&bo[j];
            f32x4 b = *(const f32x4*)&bo[j + 4];
            bf16x8 o = {f2bf(a.x), f2bf(a.y), f2bf(a.z), f2bf(a.w),
                        f2bf(b.x), f2bf(b.y), f2bf(b.z), f2bf(b.w)};
            *(bf16x8*)&bbO[j] = o;
        }
        __syncthreads();
    } else if (id < 2818) {
        const int lid = id - 2050;
        tcvt_tile(Wa, WtA, 1024, 3072, lid % 48, lid / 48, t, tile);
    } else {
        const int lid = id - 2818;
        tcvt_tile(Wo, WtO, 1024, 1024, lid % 16, lid / 16, t, tile);
    }
}

// ---------- BT GEMM, BK=64: C = A @ Bt^T + bias ----------
// BK=64 halves the barrier-drain count. 16B chunks XOR-swizzled by row
// (chunk ^= row&7): global source pre-swizzled per lane, ds_read applies the
// same XOR. SPLIT3 epilogue (fragment-order coalesced Kx/Vx/Q writeout)
// reuses the As+Bs LDS as the 128x128 Ct buffer -> total LDS 32KB.
template<int BN, bool F32OUT, bool SPLIT3>
__global__ __launch_bounds__(256) void gemm_bt(
    const short* __restrict__ A, const short* __restrict__ Bt,
    const short* __restrict__ bias, void* __restrict__ C,
    short* __restrict__ Kw, short* __restrict__ Vw, int M, int N, int K)
{
    __shared__ alignas(16) short LB[128 * 64 + BN * 64];
    short* As = LB;                  // [128][64] shorts, 16B chunks row-XOR-swizzled
    short* Bs = LB + 128 * 64;       // [BN][64]
    short* Ct = LB;                  // SPLIT3 epilogue: [128][128] (exactly 32KB)

    const int tid = threadIdx.x, w = tid >> 6, lane = tid & 63;
    const int quad = lane >> 4, l16 = lane & 15;
    constexpr int MT = (BN == 128) ? 4 : 2;
    const int wm = (BN == 128) ? (w >> 1) : w;
    const int wn = (BN == 128) ? (w & 1) : 0;
    const int m0 = blockIdx.y * 128, n0 = blockIdx.x * BN;
    // staging: one gload16 = 64 lanes x 16B = 8 rows x 128B
    const int srow = lane >> 3;                 // 0..7 within the 8-row chunk
    const int scol = ((lane & 7) ^ srow) * 8;   // pre-swizzled source chunk

    f32x4 acc[MT][4] = {};

    for (int k0 = 0; k0 < K; k0 += 64) {
        __syncthreads();
        #pragma unroll
        for (int jj = 0; jj < 4; ++jj) {
            const int rb = w * 32 + jj * 8;
            GLOAD_LDS16(&A[(size_t)(m0 + rb + srow) * K + k0 + scol], &As[rb * 64]);
        }
        if (BN == 128) {
            #pragma unroll
            for (int jj = 0; jj < 4; ++jj) {
                const int rb = w * 32 + jj * 8;
                GLOAD_LDS16(&Bt[(size_t)(n0 + rb + srow) * K + k0 + scol], &Bs[rb * 64]);
            }
        } else {
            #pragma unroll
            for (int jj = 0; jj < 2; ++jj) {
                const int rb = w * 16 + jj * 8;
                GLOAD_LDS16(&Bt[(size_t)(n0 + rb + srow) * K + k0 + scol], &Bs[rb * 64]);
            }
        }
        __syncthreads();
        #pragma unroll
        for (int half = 0; half < 2; ++half) {
            const int kc2 = half * 4 + quad;    // 16B chunk index 0..7
            bf16x8 af[MT], bfr[4];
            #pragma unroll
            for (int i = 0; i < MT; ++i) {
                const int row = wm * (MT * 16) + i * 16 + l16;
                af[i] = *(const bf16x8*)&As[row * 64 + ((kc2 ^ (row & 7)) << 3)];
            }
            #pragma unroll
            for (int i = 0; i < 4; ++i) {
                const int row = wn * 64 + i * 16 + l16;
                bfr[i] = *(const bf16x8*)&Bs[row * 64 + ((kc2 ^ (row & 7)) << 3)];
            }
            #pragma unroll
            for (int mt = 0; mt < MT; ++mt)
                #pragma unroll
                for (int nt = 0; nt < 4; ++nt)
                    acc[mt][nt] = MFMA16(af[mt], bfr[nt], acc[mt][nt]);
        }
    }

    if (SPLIT3) {
        const int g = n0 >> 10;                     // 0=q,1=k,2=v (block-uniform)
        const int lc0 = n0 & 1023;
        __syncthreads();                            // done reading As/Bs; reuse as Ct
        // ---- stage 128x128 C tile into LDS, 16B-chunk XOR swizzle ----
        if (g < 2) {
            // row-major: Ct[row][((col>>3) ^ (row&15))*8 + (col&7)]
            #pragma unroll
            for (int nt = 0; nt < 4; ++nt) {
                const int col = wn * 64 + nt * 16 + l16;
                const float bv = bf2f(bias[n0 + col]);
                const int chunk = col >> 3, wi = col & 7;
                #pragma unroll
                for (int mt = 0; mt < 4; ++mt) {
                    const int rbase = wm * 64 + mt * 16 + quad * 4;
                    #pragma unroll
                    for (int r = 0; r < 4; ++r) {
                        const int row = rbase + r;
                        float v = acc[mt][nt][r] + bv;
                        if (g == 0) v *= QK_SCALE;
                        Ct[row * 128 + (((chunk ^ (row & 15)) << 3) | wi)] = f2bf(v);
                    }
                }
            }
        } else {
            // transposed [d][key]: Ct[d][((key>>3) ^ (d&15))*8 + (key&7)],
            // 4 contiguous keys per acc reg quad -> one 8B store
            #pragma unroll
            for (int nt = 0; nt < 4; ++nt) {
                const int d = wn * 64 + nt * 16 + l16;
                const float bv = bf2f(bias[n0 + d]);
                const int dsw = d & 15;
                #pragma unroll
                for (int mt = 0; mt < 4; ++mt) {
                    const int key0 = wm * 64 + mt * 16 + quad * 4;
                    bf16x4 p = {f2bf(acc[mt][nt][0] + bv), f2bf(acc[mt][nt][1] + bv),
                                f2bf(acc[mt][nt][2] + bv), f2bf(acc[mt][nt][3] + bv)};
                    *(bf16x4*)&Ct[d * 128 + ((((key0 >> 3) ^ dsw) << 3) | (key0 & 7))] = p;
                }
            }
        }
        __syncthreads();
        // ---- coalesced writeout ----
        const int batch = m0 >> 11;
        const int kc0 = (m0 & 2047) >> 6;           // even; tile covers kc0, kc0+1
        const int head0 = lc0 >> 6;                 // even; tile covers head0, head0+1
        if (g == 0) {
            short* dst = (short*)C;                 // Qw, row-major [4096][1024]
            #pragma unroll
            for (int i = 0; i < 8; ++i) {
                const int idx = i * 256 + tid;      // 0..2047
                const int row = idx >> 4, chunk = idx & 15;
                bf16x8 v = *(const bf16x8*)&Ct[row * 128 + ((chunk ^ (row & 15)) << 3)];
                *(bf16x8*)&dst[(size_t)(m0 + row) * 1024 + lc0 + chunk * 8] = v;
            }
        } else if (g == 1) {
            // Kx[bh][kc][c=(s*2+h2)*64+lane][j] = K[kc*64+s*16+l16][h2*32+quad*8+j]
            #pragma unroll
            for (int i = 0; i < 8; ++i) {
                const int idx = i * 256 + tid;
                const int qd = idx >> 9, c = idx & 511;
                const int kcL = qd >> 1, headL = qd & 1;
                const int s = c >> 7, h2 = (c >> 6) & 1;
                const int l16c = c & 15, quadc = (c >> 4) & 3;
                const int row = kcL * 64 + s * 16 + l16c;
                const int colc = headL * 8 + h2 * 4 + quadc;
                bf16x8 v = *(const bf16x8*)&Ct[row * 128 + ((colc ^ (row & 15)) << 3)];
                const int bh = batch * 16 + head0 + headL, kc = kc0 + kcL;
                *(bf16x8*)&Kw[((size_t)(bh * 32 + kc) * 512 + c) * 8] = v;
            }
        } else {
            // Vx[bh][kc][c=(h2*4+dt)*64+lane][j] = V[kc*64+h2*32+quad*8+j][dt*16+l16]
            #pragma unroll
            for (int i = 0; i < 8; ++i) {
                const int idx = i * 256 + tid;
                const int qd = idx >> 9, c = idx & 511;
                const int kcL = qd >> 1, headL = qd & 1;
                const int h2 = c >> 8, dt = (c >> 6) & 3;
                const int l16c = c & 15, quadc = (c >> 4) & 3;
                const int d = headL * 64 + dt * 16 + l16c;
                const int keyc = kcL * 8 + h2 * 4 + quadc;
                bf16x8 v = *(const bf16x8*)&Ct[d * 128 + ((keyc ^ (d & 15)) << 3)];
                const int bh = batch * 16 + head0 + headL, kc = kc0 + kcL;
                *(bf16x8*)&Vw[((size_t)(bh * 32 + kc) * 512 + c) * 8] = v;
            }
        }
    } else {
        #pragma unroll
        for (int nt = 0; nt < 4; ++nt) {
            const int col = n0 + wn * 64 + nt * 16 + l16;
            const float bv = bf2f(bias[col]);
            #pragma unroll
            for (int mt = 0; mt < MT; ++mt) {
                const int row = m0 + wm * (MT * 16) + mt * 16 + quad * 4;
                #pragma unroll
                for (int r = 0; r < 4; ++r) {
                    float v = acc[mt][nt][r] + bv;
                    if (F32OUT) ((float*)C)[(size_t)(row + r) * N + col] = v;
                    else        ((short*)C)[(size_t)(row + r) * N + col] = f2bf(v);
                }
            }
        }
    }
}

// ---------- causal flash attention, LDS-staged K/V shared by 2 tile-pairs ----------
// Round-4 rewrite: round-3 counters showed wave-count-invariant MfmaUtil/
// VALUBusy/dur => K/V fan-out through L2 was the binding resource (~15.6 TB/s
// demand: every wave re-loaded the full 8KB K and V tile per step). Now one
// block = 2 pairs {2g,63-2g},{2g+1,62-2g} (4 waves, 64 q-rows) and each kc
// step stages K+V ONCE into double-buffered LDS via global_load_lds (Kx/Vx
// fragment layout is linear -> direct copy, conflict-free b128 reads).
// All 4 waves share identical diagA=g, diagB=31-g: zero divergence, one
// barrier per step, no cross-wave combine. L2 traffic: 795 -> 200 MB.
__global__ __launch_bounds__(256) void attn_kernel(
    const short* __restrict__ Qw, const short* __restrict__ Kx,
    const short* __restrict__ Vx, short* __restrict__ comb)
{
    __shared__ alignas(16) short KV[2][2][4096];      // [buf][K/V][tile] 32KB
    __shared__ alignas(16) short Ps[4][2][16 * 72];   // [wave][tile A/B] 18KB

    const int tid = threadIdx.x, w4 = tid >> 6, lane = tid & 63;
    const int p = w4 >> 1;         // pair index within block
    const int w = w4 & 1;          // 16-row q sub-tile within the 32-row tiles
    const int quad = lane >> 4, l16 = lane & 15;
    const int bh = blockIdx.x;
    const int g = blockIdx.y;                       // 0..15
    const int tA = 2 * g + p, tB = 63 - tA;
    const int batch = bh >> 4, head = bh & 15;
    const size_t rowbase = (size_t)batch * 2048;
    const int hcol = head * 64;
    const int q0A = tA * 32 + w * 16, q0B = tB * 32 + w * 16;
    const int diagA = g;                            // tA>>1 for both p
    const int maxD = 31 - g;                        // tB>>1 for both p
    const short* Kxbh = Kx + (size_t)bh * 131072;
    const short* Vxbh = Vx + (size_t)bh * 131072;
    const int lofs = lane * 8;
    short* pwA = &Ps[w4][0][0];
    short* pwB = &Ps[w4][1][0];

    // Q fragments (B-operand: q = l16, d = quad*8+j (+32))
    bf16x8 qfA[2], qfB[2];
    {
        const short* pa = &Qw[(rowbase + q0A + l16) * 1024 + hcol];
        const short* pb = &Qw[(rowbase + q0B + l16) * 1024 + hcol];
        qfA[0] = *(const bf16x8*)(pa + quad * 8);
        qfA[1] = *(const bf16x8*)(pa + 32 + quad * 8);
        qfB[0] = *(const bf16x8*)(pb + quad * 8);
        qfB[1] = *(const bf16x8*)(pb + 32 + quad * 8);
    }

    f32x4 otA[4] = {}, otB[4] = {};
    float laccA = 0.f, laccB = 0.f;

    // per-wave staging slices: wave w4 stages chunks {j*256 + w4*64 + lane}
    const int sbase = w4 * 64;                      // chunk base for this wave

    // prologue: stage kc=0
    {
        #pragma unroll
        for (int j = 0; j < 2; ++j) {
            GLOAD_LDS16(&Kxbh[(size_t)(j * 256 + sbase + lane) * 8], &KV[0][0][(j * 256 + sbase) * 8]);
            GLOAD_LDS16(&Vxbh[(size_t)(j * 256 + sbase + lane) * 8], &KV[0][1][(j * 256 + sbase) * 8]);
        }
    }
    __syncthreads();

    int cur = 0;
    for (int kc = 0; kc <= maxD; ++kc) {
        const bool actA = (kc <= diagA);
        const int key0 = kc * 64;

        // ---- stage next step's K/V into the other buffer (off critical path) ----
        if (kc < maxD) {
            const size_t nb = (size_t)(kc + 1) * 4096;
            #pragma unroll
            for (int j = 0; j < 2; ++j) {
                GLOAD_LDS16(&Kxbh[nb + (size_t)(j * 256 + sbase + lane) * 8], &KV[cur ^ 1][0][(j * 256 + sbase) * 8]);
                GLOAD_LDS16(&Vxbh[nb + (size_t)(j * 256 + sbase + lane) * 8], &KV[cur ^ 1][1][(j * 256 + sbase) * 8]);
            }
        }

        // ---- K fragments from LDS ----
        bf16x8 kf[4][2];
        #pragma unroll
        for (int s = 0; s < 4; ++s) {
            kf[s][0] = *(const bf16x8*)&KV[cur][0][(s * 2 + 0) * 512 + lofs];
            kf[s][1] = *(const bf16x8*)&KV[cur][0][(s * 2 + 1) * 512 + lofs];
        }

        // ---- QK (S^T = K.Q^T) ----
        f32x4 svA[4], svB[4];
        #pragma unroll
        for (int s = 0; s < 4; ++s) {
            f32x4 a = {0.f, 0.f, 0.f, 0.f};
            a = MFMA16(kf[s][0], qfB[0], a);
            a = MFMA16(kf[s][1], qfB[1], a);
            svB[s] = a;
            if (actA) {
                f32x4 b = {0.f, 0.f, 0.f, 0.f};
                b = MFMA16(kf[s][0], qfA[0], b);
                b = MFMA16(kf[s][1], qfA[1], b);
                svA[s] = b;
            }
        }

        // ---- V fragments from LDS (issued here; lgkm hides under softmax) ----
        bf16x8 vf[2][4];
        #pragma unroll
        for (int hh = 0; hh < 2; ++hh)
            #pragma unroll
            for (int dt = 0; dt < 4; ++dt)
                vf[hh][dt] = *(const bf16x8*)&KV[cur][1][(hh * 4 + dt) * 512 + lofs];

        // ---- softmax + P^T -> per-wave LDS ----
        if (kc == maxD) {
            const int qq = q0B + l16;
            #pragma unroll
            for (int s = 0; s < 4; ++s) {
                const int keyb = key0 + s * 16 + quad * 4;
                #pragma unroll
                for (int r = 0; r < 4; ++r)
                    svB[s][r] = (keyb + r <= qq) ? svB[s][r] : -1e30f;
            }
        }
        #pragma unroll
        for (int s = 0; s < 4; ++s) {
            #pragma unroll
            for (int r = 0; r < 4; ++r) svB[s][r] = exp2f(svB[s][r]);
            laccB += (svB[s][0] + svB[s][1]) + (svB[s][2] + svB[s][3]);
            *(unsigned*)&pwB[l16 * 72 + s * 16 + quad * 4]     = pk_bf16(svB[s][0], svB[s][1]);
            *(unsigned*)&pwB[l16 * 72 + s * 16 + quad * 4 + 2] = pk_bf16(svB[s][2], svB[s][3]);
        }
        if (actA) {
            if (kc == diagA) {
                const int qq = q0A + l16;
                #pragma unroll
                for (int s = 0; s < 4; ++s) {
                    const int keyb = key0 + s * 16 + quad * 4;
                    #pragma unroll
                    for (int r = 0; r < 4; ++r)
                        svA[s][r] = (keyb + r <= qq) ? svA[s][r] : -1e30f;
                }
            }
            #pragma unroll
            for (int s = 0; s < 4; ++s) {
                #pragma unroll
                for (int r = 0; r < 4; ++r) svA[s][r] = exp2f(svA[s][r]);
                laccA += (svA[s][0] + svA[s][1]) + (svA[s][2] + svA[s][3]);
                *(unsigned*)&pwA[l16 * 72 + s * 16 + quad * 4]     = pk_bf16(svA[s][0], svA[s][1]);
                *(unsigned*)&pwA[l16 * 72 + s * 16 + quad * 4 + 2] = pk_bf16(svA[s][2], svA[s][3]);
            }
        }

        // ---- PV (O^T += V^T.P^T); wave-internal DS is in-order ----
        {
            bf16x8 pfB0 = *(const bf16x8*)&pwB[l16 * 72 + quad * 8];
            bf16x8 pfB1 = *(const bf16x8*)&pwB[l16 * 72 + 32 + quad * 8];
            #pragma unroll
            for (int dt = 0; dt < 4; ++dt) {
                otB[dt] = MFMA16(vf[0][dt], pfB0, otB[dt]);
                otB[dt] = MFMA16(vf[1][dt], pfB1, otB[dt]);
            }
            if (actA) {
                bf16x8 pfA0 = *(const bf16x8*)&pwA[l16 * 72 + quad * 8];
                bf16x8 pfA1 = *(const bf16x8*)&pwA[l16 * 72 + 32 + quad * 8];
                #pragma unroll
                for (int dt = 0; dt < 4; ++dt) {
                    otA[dt] = MFMA16(vf[0][dt], pfA0, otA[dt]);
                    otA[dt] = MFMA16(vf[1][dt], pfA1, otA[dt]);
                }
            }
        }

        // drain staging (vmcnt) + release buffers; compiler emits full waitcnt
        __syncthreads();
        cur ^= 1;
    }

    // ---- l reduction (lanes sharing l16 across quads) + epilogue ----
    laccA += __shfl_xor(laccA, 16);
    laccA += __shfl_xor(laccA, 32);
    laccB += __shfl_xor(laccB, 16);
    laccB += __shfl_xor(laccB, 32);
    const float invA = 1.0f / laccA, invB = 1.0f / laccB;

    #pragma unroll
    for (int dt = 0; dt < 4; ++dt) {
        *(unsigned*)&pwA[l16 * 72 + dt * 16 + quad * 4]     = pk_bf16(otA[dt][0] * invA, otA[dt][1] * invA);
        *(unsigned*)&pwA[l16 * 72 + dt * 16 + quad * 4 + 2] = pk_bf16(otA[dt][2] * invA, otA[dt][3] * invA);
        *(unsigned*)&pwB[l16 * 72 + dt * 16 + quad * 4]     = pk_bf16(otB[dt][0] * invB, otB[dt][1] * invB);
        *(unsigned*)&pwB[l16 * 72 + dt * 16 + quad * 4 + 2] = pk_bf16(otB[dt][2] * invB, otB[dt][3] * invB);
    }
    {
        const int qr = lane >> 2, dc = (lane & 3) * 16;
        bf16x8 a0 = *(const bf16x8*)&pwA[qr * 72 + dc];
        bf16x8 a1 = *(const bf16x8*)&pwA[qr * 72 + dc + 8];
        short* dstA = &comb[(rowbase + q0A + qr) * 1024 + hcol + dc];
        *(bf16x8*)dstA = a0;
        *(bf16x8*)(dstA + 8) = a1;
        bf16x8 b0 = *(const bf16x8*)&pwB[qr * 72 + dc];
        bf16x8 b1 = *(const bf16x8*)&pwB[qr * 72 + dc + 8];
        short* dstB = &comb[(rowbase + q0B + qr) * 1024 + hcol + dc];
        *(bf16x8*)dstB = b0;
        *(bf16x8*)(dstB + 8) = b1;
    }
}

// ---------- launch ----------
extern "C" void kernel_launch(void* const* d_in, const int* in_sizes, int n_in,
                              void* d_out, int out_size, void* d_ws, size_t ws_size,
                              hipStream_t stream)
{
    const float* enc = (const float*)d_in[0];
    const float* Wa  = (const float*)d_in[1];
    const float* ba  = (const float*)d_in[2];
    const float* Wo  = (const float*)d_in[3];
    const float* bo  = (const float*)d_in[4];
    float* out = (float*)d_out;

    // layout (41 MB peak):
    // [0,8)   Abf (dead after gemm1) -> comb
    // [8,10)  WtO    [10,11) biases
    // [11,17) WtA    [17,25) Kx    [25,33) Vx    [33,41) Qw
    char* ws = (char*)d_ws;
    short* Abf  = (short*)ws;
    short* comb = (short*)ws;
    short* WtO  = (short*)(ws + ((size_t)8 << 20));
    short* bbA  = (short*)(ws + ((size_t)10 << 20));
    short* bbO  = (short*)(ws + ((size_t)10 << 20) + 16384);
    short* WtA  = (short*)(ws + ((size_t)11 << 20));
    short* Kx   = (short*)(ws + ((size_t)17 << 20));
    short* Vx   = (short*)(ws + ((size_t)25 << 20));
    short* Qw   = (short*)(ws + ((size_t)33 << 20));

    prep_kernel<<<3074, 256, 0, stream>>>(enc, Wa, ba, Wo, bo, Abf, WtA, bbA, WtO, bbO);
    gemm_bt<128, false, true><<<dim3(24, 32), 256, 0, stream>>>(
        Abf, WtA, bbA, Qw, Kx, Vx, 4096, 3072, 1024);
    attn_kernel<<<dim3(32, 16), 256, 0, stream>>>(Qw, Kx, Vx, comb);
    gemm_bt<64, true, false><<<dim3(16, 32), 256, 0, stream>>>(
        comb, WtO, bbO, out, nullptr, nullptr, 4096, 1024, 1024);
}

// Round 5
// 188.981 us; speedup vs baseline: 1.0053x; 1.0053x over previous
//
#include <hip/hip_runtime.h>
#include <hip/hip_bf16.h>

// ---------- types / helpers ----------
typedef __attribute__((ext_vector_type(8))) short bf16x8;   // 8 bf16 = 4 VGPRs
typedef __attribute__((ext_vector_type(4))) short bf16x4;
typedef __attribute__((ext_vector_type(4))) float f32x4;

__device__ __forceinline__ short f2bf(float f) {
    unsigned u = __float_as_uint(f);
    u += 0x7fff + ((u >> 16) & 1);          // round-to-nearest-even
    return (short)(u >> 16);
}
__device__ __forceinline__ float bf2f(short s) {
    return __uint_as_float(((unsigned)(unsigned short)s) << 16);
}
__device__ __forceinline__ unsigned pk_bf16(float lo, float hi) {
    __hip_bfloat162 t = __float22bfloat162_rn(make_float2(lo, hi));
    unsigned u;
    __builtin_memcpy(&u, &t, 4);
    return u;
}

#define GLOAD_LDS16(gp, lp)                                                            \
    __builtin_amdgcn_global_load_lds(                                                  \
        (const __attribute__((address_space(1))) unsigned*)(gp),                       \
        (__attribute__((address_space(3))) unsigned*)(lp), 16, 0, 0)

#define QK_SCALE 0.180336879f   // (1/sqrt(64)) * log2(e), folded into q at GEMM1
#define MFMA16(a, b, c) __builtin_amdgcn_mfma_f32_16x16x32_bf16((a), (b), (c), 0, 0, 0)

// ---------- fused prep: enc->bf16, biases->bf16, Wa/Wo -> transposed bf16 ----------
__device__ __forceinline__ void tcvt_tile(const float* __restrict__ W, short* __restrict__ Wt,
                                          int K, int N, int bx, int by, int t,
                                          short (*tile)[72]) {
    const int k0 = by * 64, n0 = bx * 64;
    #pragma unroll
    for (int jj = 0; jj < 4; ++jj) {
        int row = jj * 16 + (t >> 4);
        int col = (t & 15) * 4;
        f32x4 v = *(const f32x4*)&W[(size_t)(k0 + row) * N + n0 + col];
        bf16x4 b = {f2bf(v.x), f2bf(v.y), f2bf(v.z), f2bf(v.w)};
        *(bf16x4*)&tile[row][col] = b;
    }
    __syncthreads();
    const int nr = t >> 2, kc = (t & 3) * 16;
    bf16x8 o0, o1;
    #pragma unroll
    for (int j = 0; j < 8; ++j) { o0[j] = tile[kc + j][nr]; o1[j] = tile[kc + 8 + j][nr]; }
    short* dst = &Wt[(size_t)(n0 + nr) * K + k0 + kc];
    *(bf16x8*)dst = o0;
    *(bf16x8*)(dst + 8) = o1;
}

__global__ __launch_bounds__(256) void prep_kernel(
    const float* __restrict__ enc, const float* __restrict__ Wa,
    const float* __restrict__ ba, const float* __restrict__ Wo,
    const float* __restrict__ bo, short* __restrict__ Abf,
    short* __restrict__ WtA, short* __restrict__ bbA,
    short* __restrict__ WtO, short* __restrict__ bbO)
{
    __shared__ alignas(16) short tile[64][72];
    const int id = blockIdx.x, t = threadIdx.x;
    if (id < 2048) {
        const int i = id * 2048 + t * 8;
        f32x4 a = *(const f32x4*)&enc[i];
        f32x4 b = *(const f32x4*)&enc[i + 4];
        bf16x8 o = {f2bf(a.x), f2bf(a.y), f2bf(a.z), f2bf(a.w),
                    f2bf(b.x), f2bf(b.y), f2bf(b.z), f2bf(b.w)};
        *(bf16x8*)&Abf[i] = o;
    } else if (id == 2048) {
        for (int j = t * 8; j < 3072; j += 2048) {
            f32x4 a = *(const f32x4*)&ba[j];
            f32x4 b = *(const f32x4*)&ba[j + 4];
            bf16x8 o = {f2bf(a.x), f2bf(a.y), f2bf(a.z), f2bf(a.w),
                        f2bf(b.x), f2bf(b.y), f2bf(b.z), f2bf(b.w)};
            *(bf16x8*)&bbA[j] = o;
        }
    } else if (id == 2049) {
        if (t < 128) {
            const int j = t * 8;
            f32x4 a = *(const f32x4*)&bo[j];
            f32x4 b = *(const f32x4*)&bo[j + 4];
            bf16x8 o = {f2bf(a.x), f2bf(a.y), f2bf(a.z), f2bf(a.w),
                        f2bf(b.x), f2bf(b.y), f2bf(b.z), f2bf(b.w)};
            *(bf16x8*)&bbO[j] = o;
        }
        __syncthreads();
    } else if (id < 2818) {
        const int lid = id - 2050;
        tcvt_tile(Wa, WtA, 1024, 3072, lid % 48, lid / 48, t, tile);
    } else {
        const int lid = id - 2818;
        tcvt_tile(Wo, WtO, 1024, 1024, lid % 16, lid / 16, t, tile);
    }
}

// ---------- BT GEMM, BK=64: C = A @ Bt^T + bias ----------
// BK=64 halves the barrier-drain count. 16B chunks XOR-swizzled by row
// (chunk ^= row&7): global source pre-swizzled per lane, ds_read applies the
// same XOR. SPLIT3 epilogue (fragment-order coalesced Kx/Vx/Q writeout)
// reuses the As+Bs LDS as the 128x128 Ct buffer -> total LDS 32KB.
template<int BN, bool F32OUT, bool SPLIT3>
__global__ __launch_bounds__(256) void gemm_bt(
    const short* __restrict__ A, const short* __restrict__ Bt,
    const short* __restrict__ bias, void* __restrict__ C,
    short* __restrict__ Kw, short* __restrict__ Vw, int M, int N, int K)
{
    __shared__ alignas(16) short LB[128 * 64 + BN * 64];
    short* As = LB;                  // [128][64] shorts, 16B chunks row-XOR-swizzled
    short* Bs = LB + 128 * 64;       // [BN][64]
    short* Ct = LB;                  // SPLIT3 epilogue: [128][128] (exactly 32KB)

    const int tid = threadIdx.x, w = tid >> 6, lane = tid & 63;
    const int quad = lane >> 4, l16 = lane & 15;
    constexpr int MT = (BN == 128) ? 4 : 2;
    const int wm = (BN == 128) ? (w >> 1) : w;
    const int wn = (BN == 128) ? (w & 1) : 0;
    const int m0 = blockIdx.y * 128, n0 = blockIdx.x * BN;
    // staging: one gload16 = 64 lanes x 16B = 8 rows x 128B
    const int srow = lane >> 3;                 // 0..7 within the 8-row chunk
    const int scol = ((lane & 7) ^ srow) * 8;   // pre-swizzled source chunk

    f32x4 acc[MT][4] = {};

    for (int k0 = 0; k0 < K; k0 += 64) {
        __syncthreads();
        #pragma unroll
        for (int jj = 0; jj < 4; ++jj) {
            const int rb = w * 32 + jj * 8;
            GLOAD_LDS16(&A[(size_t)(m0 + rb + srow) * K + k0 + scol], &As[rb * 64]);
        }
        if (BN == 128) {
            #pragma unroll
            for (int jj = 0; jj < 4; ++jj) {
                const int rb = w * 32 + jj * 8;
                GLOAD_LDS16(&Bt[(size_t)(n0 + rb + srow) * K + k0 + scol], &Bs[rb * 64]);
            }
        } else {
            #pragma unroll
            for (int jj = 0; jj < 2; ++jj) {
                const int rb = w * 16 + jj * 8;
                GLOAD_LDS16(&Bt[(size_t)(n0 + rb + srow) * K + k0 + scol], &Bs[rb * 64]);
            }
        }
        __syncthreads();
        #pragma unroll
        for (int half = 0; half < 2; ++half) {
            const int kc2 = half * 4 + quad;    // 16B chunk index 0..7
            bf16x8 af[MT], bfr[4];
            #pragma unroll
            for (int i = 0; i < MT; ++i) {
                const int row = wm * (MT * 16) + i * 16 + l16;
                af[i] = *(const bf16x8*)&As[row * 64 + ((kc2 ^ (row & 7)) << 3)];
            }
            #pragma unroll
            for (int i = 0; i < 4; ++i) {
                const int row = wn * 64 + i * 16 + l16;
                bfr[i] = *(const bf16x8*)&Bs[row * 64 + ((kc2 ^ (row & 7)) << 3)];
            }
            #pragma unroll
            for (int mt = 0; mt < MT; ++mt)
                #pragma unroll
                for (int nt = 0; nt < 4; ++nt)
                    acc[mt][nt] = MFMA16(af[mt], bfr[nt], acc[mt][nt]);
        }
    }

    if (SPLIT3) {
        const int g = n0 >> 10;                     // 0=q,1=k,2=v (block-uniform)
        const int lc0 = n0 & 1023;
        __syncthreads();                            // done reading As/Bs; reuse as Ct
        // ---- stage 128x128 C tile into LDS, 16B-chunk XOR swizzle ----
        if (g < 2) {
            // row-major: Ct[row][((col>>3) ^ (row&15))*8 + (col&7)]
            #pragma unroll
            for (int nt = 0; nt < 4; ++nt) {
                const int col = wn * 64 + nt * 16 + l16;
                const float bv = bf2f(bias[n0 + col]);
                const int chunk = col >> 3, wi = col & 7;
                #pragma unroll
                for (int mt = 0; mt < 4; ++mt) {
                    const int rbase = wm * 64 + mt * 16 + quad * 4;
                    #pragma unroll
                    for (int r = 0; r < 4; ++r) {
                        const int row = rbase + r;
                        float v = acc[mt][nt][r] + bv;
                        if (g == 0) v *= QK_SCALE;
                        Ct[row * 128 + (((chunk ^ (row & 15)) << 3) | wi)] = f2bf(v);
                    }
                }
            }
        } else {
            // transposed [d][key]: Ct[d][((key>>3) ^ (d&15))*8 + (key&7)],
            // 4 contiguous keys per acc reg quad -> one 8B store
            #pragma unroll
            for (int nt = 0; nt < 4; ++nt) {
                const int d = wn * 64 + nt * 16 + l16;
                const float bv = bf2f(bias[n0 + d]);
                const int dsw = d & 15;
                #pragma unroll
                for (int mt = 0; mt < 4; ++mt) {
                    const int key0 = wm * 64 + mt * 16 + quad * 4;
                    bf16x4 p = {f2bf(acc[mt][nt][0] + bv), f2bf(acc[mt][nt][1] + bv),
                                f2bf(acc[mt][nt][2] + bv), f2bf(acc[mt][nt][3] + bv)};
                    *(bf16x4*)&Ct[d * 128 + ((((key0 >> 3) ^ dsw) << 3) | (key0 & 7))] = p;
                }
            }
        }
        __syncthreads();
        // ---- coalesced writeout ----
        const int batch = m0 >> 11;
        const int kc0 = (m0 & 2047) >> 6;           // even; tile covers kc0, kc0+1
        const int head0 = lc0 >> 6;                 // even; tile covers head0, head0+1
        if (g == 0) {
            short* dst = (short*)C;                 // Qw, row-major [4096][1024]
            #pragma unroll
            for (int i = 0; i < 8; ++i) {
                const int idx = i * 256 + tid;      // 0..2047
                const int row = idx >> 4, chunk = idx & 15;
                bf16x8 v = *(const bf16x8*)&Ct[row * 128 + ((chunk ^ (row & 15)) << 3)];
                *(bf16x8*)&dst[(size_t)(m0 + row) * 1024 + lc0 + chunk * 8] = v;
            }
        } else if (g == 1) {
            // Kx[bh][kc][c=(s*2+h2)*64+lane][j] = K[kc*64+s*16+l16][h2*32+quad*8+j]
            #pragma unroll
            for (int i = 0; i < 8; ++i) {
                const int idx = i * 256 + tid;
                const int qd = idx >> 9, c = idx & 511;
                const int kcL = qd >> 1, headL = qd & 1;
                const int s = c >> 7, h2 = (c >> 6) & 1;
                const int l16c = c & 15, quadc = (c >> 4) & 3;
                const int row = kcL * 64 + s * 16 + l16c;
                const int colc = headL * 8 + h2 * 4 + quadc;
                bf16x8 v = *(const bf16x8*)&Ct[row * 128 + ((colc ^ (row & 15)) << 3)];
                const int bh = batch * 16 + head0 + headL, kc = kc0 + kcL;
                *(bf16x8*)&Kw[((size_t)(bh * 32 + kc) * 512 + c) * 8] = v;
            }
        } else {
            // Vx[bh][kc][c=(h2*4+dt)*64+lane][j] = V[kc*64+h2*32+quad*8+j][dt*16+l16]
            #pragma unroll
            for (int i = 0; i < 8; ++i) {
                const int idx = i * 256 + tid;
                const int qd = idx >> 9, c = idx & 511;
                const int kcL = qd >> 1, headL = qd & 1;
                const int h2 = c >> 8, dt = (c >> 6) & 3;
                const int l16c = c & 15, quadc = (c >> 4) & 3;
                const int d = headL * 64 + dt * 16 + l16c;
                const int keyc = kcL * 8 + h2 * 4 + quadc;
                bf16x8 v = *(const bf16x8*)&Ct[d * 128 + ((keyc ^ (d & 15)) << 3)];
                const int bh = batch * 16 + head0 + headL, kc = kc0 + kcL;
                *(bf16x8*)&Vw[((size_t)(bh * 32 + kc) * 512 + c) * 8] = v;
            }
        }
    } else {
        #pragma unroll
        for (int nt = 0; nt < 4; ++nt) {
            const int col = n0 + wn * 64 + nt * 16 + l16;
            const float bv = bf2f(bias[col]);
            #pragma unroll
            for (int mt = 0; mt < MT; ++mt) {
                const int row = m0 + wm * (MT * 16) + mt * 16 + quad * 4;
                #pragma unroll
                for (int r = 0; r < 4; ++r) {
                    float v = acc[mt][nt][r] + bv;
                    if (F32OUT) ((float*)C)[(size_t)(row + r) * N + col] = v;
                    else        ((short*)C)[(size_t)(row + r) * N + col] = f2bf(v);
                }
            }
        }
    }
}

// ---------- causal flash attention: LDS-staged K/V, counted-vmcnt pipeline ----------
// Round-5: round-4's __syncthreads forced a vmcnt(0) drain every step,
// serializing the "prefetch" into the critical path (m97 barrier-drain).
// Now triple-buffered KV + issue batch(kc+2) at step top + raw s_barrier with
// asm s_waitcnt vmcnt(4): the just-issued batch stays in flight across the
// barrier, only the batch needed next step is drained (T3/T4, m218 lever).
// Q-loads drained once pre-loop so in-loop vmcnt counts are statically exact;
// staging index clamped to maxD so every step issues exactly 4 loads.
__global__ __launch_bounds__(256) void attn_kernel(
    const short* __restrict__ Qw, const short* __restrict__ Kx,
    const short* __restrict__ Vx, short* __restrict__ comb)
{
    __shared__ alignas(16) short KV[3][2][4096];      // [buf][K/V][tile] 48KB
    __shared__ alignas(16) short Ps[4][2][16 * 72];   // [wave][tile A/B] 18KB

    const int tid = threadIdx.x, w4 = tid >> 6, lane = tid & 63;
    const int p = w4 >> 1;         // pair index within block
    const int w = w4 & 1;          // 16-row q sub-tile within the 32-row tiles
    const int quad = lane >> 4, l16 = lane & 15;
    const int bh = blockIdx.x;
    const int g = blockIdx.y;                       // 0..15
    const int tA = 2 * g + p, tB = 63 - tA;
    const int batch = bh >> 4, head = bh & 15;
    const size_t rowbase = (size_t)batch * 2048;
    const int hcol = head * 64;
    const int q0A = tA * 32 + w * 16, q0B = tB * 32 + w * 16;
    const int diagA = g;                            // tA>>1 for both p
    const int maxD = 31 - g;                        // tB>>1 for both p
    const short* Kxbh = Kx + (size_t)bh * 131072;
    const short* Vxbh = Vx + (size_t)bh * 131072;
    const int lofs = lane * 8;
    short* pwA = &Ps[w4][0][0];
    short* pwB = &Ps[w4][1][0];

    // Q fragments (B-operand: q = l16, d = quad*8+j (+32))
    bf16x8 qfA[2], qfB[2];
    {
        const short* pa = &Qw[(rowbase + q0A + l16) * 1024 + hcol];
        const short* pb = &Qw[(rowbase + q0B + l16) * 1024 + hcol];
        qfA[0] = *(const bf16x8*)(pa + quad * 8);
        qfA[1] = *(const bf16x8*)(pa + 32 + quad * 8);
        qfB[0] = *(const bf16x8*)(pb + quad * 8);
        qfB[1] = *(const bf16x8*)(pb + 32 + quad * 8);
    }
    // drain Q loads so in-loop vmcnt counts are statically exact
    asm volatile("s_waitcnt vmcnt(0)" ::: "memory");

    f32x4 otA[4] = {}, otB[4] = {};
    float laccA = 0.f, laccB = 0.f;

    // per-wave staging slice: wave w4 stages chunks {j*256 + w4*64 + lane}
    const int sbase = w4 * 64;

    // stage(kcs, buf): 4 global_load_lds (2 K + 2 V), 16KB/block-step total
    #define STAGE_KV(kcs, buf)                                                              \
        do {                                                                                \
            const size_t nb_ = (size_t)(kcs)*4096;                                          \
            _Pragma("unroll")                                                               \
            for (int j = 0; j < 2; ++j) {                                                   \
                GLOAD_LDS16(&Kxbh[nb_ + (size_t)(j * 256 + sbase + lane) * 8],              \
                            &KV[buf][0][(j * 256 + sbase) * 8]);                            \
                GLOAD_LDS16(&Vxbh[nb_ + (size_t)(j * 256 + sbase + lane) * 8],              \
                            &KV[buf][1][(j * 256 + sbase) * 8]);                            \
            }                                                                               \
        } while (0)

    // prologue: stage kc=0 -> buf0, kc=1 -> buf1 (maxD >= 16, always valid)
    STAGE_KV(0, 0);
    STAGE_KV(1, 1);
    asm volatile("s_waitcnt vmcnt(4)" ::: "memory");   // drain batch(0), keep batch(1)
    __builtin_amdgcn_s_barrier();
    __builtin_amdgcn_sched_barrier(0);

    int cur = 0;
    for (int kc = 0; kc <= maxD; ++kc) {
        const bool actA = (kc <= diagA);
        const int key0 = kc * 64;

        // ---- issue batch(kc+2) into buf (kc+2)%3 (clamped: uniform 4 loads/step) ----
        {
            const int ks = (kc + 2 <= maxD) ? kc + 2 : maxD;
            const int wb = (cur + 2 >= 3) ? cur - 1 : cur + 2;
            STAGE_KV(ks, wb);
        }

        // ---- K fragments from LDS ----
        bf16x8 kf[4][2];
        #pragma unroll
        for (int s = 0; s < 4; ++s) {
            kf[s][0] = *(const bf16x8*)&KV[cur][0][(s * 2 + 0) * 512 + lofs];
            kf[s][1] = *(const bf16x8*)&KV[cur][0][(s * 2 + 1) * 512 + lofs];
        }

        // ---- QK (S^T = K.Q^T) ----
        f32x4 svA[4], svB[4];
        #pragma unroll
        for (int s = 0; s < 4; ++s) {
            f32x4 a = {0.f, 0.f, 0.f, 0.f};
            a = MFMA16(kf[s][0], qfB[0], a);
            a = MFMA16(kf[s][1], qfB[1], a);
            svB[s] = a;
            if (actA) {
                f32x4 b = {0.f, 0.f, 0.f, 0.f};
                b = MFMA16(kf[s][0], qfA[0], b);
                b = MFMA16(kf[s][1], qfA[1], b);
                svA[s] = b;
            }
        }

        // ---- V fragments from LDS (lgkm hides under softmax) ----
        bf16x8 vf[2][4];
        #pragma unroll
        for (int hh = 0; hh < 2; ++hh)
            #pragma unroll
            for (int dt = 0; dt < 4; ++dt)
                vf[hh][dt] = *(const bf16x8*)&KV[cur][1][(hh * 4 + dt) * 512 + lofs];

        // ---- softmax + P^T -> per-wave LDS ----
        if (kc == maxD) {
            const int qq = q0B + l16;
            #pragma unroll
            for (int s = 0; s < 4; ++s) {
                const int keyb = key0 + s * 16 + quad * 4;
                #pragma unroll
                for (int r = 0; r < 4; ++r)
                    svB[s][r] = (keyb + r <= qq) ? svB[s][r] : -1e30f;
            }
        }
        #pragma unroll
        for (int s = 0; s < 4; ++s) {
            #pragma unroll
            for (int r = 0; r < 4; ++r) svB[s][r] = exp2f(svB[s][r]);
            laccB += (svB[s][0] + svB[s][1]) + (svB[s][2] + svB[s][3]);
            *(unsigned*)&pwB[l16 * 72 + s * 16 + quad * 4]     = pk_bf16(svB[s][0], svB[s][1]);
            *(unsigned*)&pwB[l16 * 72 + s * 16 + quad * 4 + 2] = pk_bf16(svB[s][2], svB[s][3]);
        }
        if (actA) {
            if (kc == diagA) {
                const int qq = q0A + l16;
                #pragma unroll
                for (int s = 0; s < 4; ++s) {
                    const int keyb = key0 + s * 16 + quad * 4;
                    #pragma unroll
                    for (int r = 0; r < 4; ++r)
                        svA[s][r] = (keyb + r <= qq) ? svA[s][r] : -1e30f;
                }
            }
            #pragma unroll
            for (int s = 0; s < 4; ++s) {
                #pragma unroll
                for (int r = 0; r < 4; ++r) svA[s][r] = exp2f(svA[s][r]);
                laccA += (svA[s][0] + svA[s][1]) + (svA[s][2] + svA[s][3]);
                *(unsigned*)&pwA[l16 * 72 + s * 16 + quad * 4]     = pk_bf16(svA[s][0], svA[s][1]);
                *(unsigned*)&pwA[l16 * 72 + s * 16 + quad * 4 + 2] = pk_bf16(svA[s][2], svA[s][3]);
            }
        }

        // ---- PV (O^T += V^T.P^T); wave-internal DS is in-order ----
        {
            bf16x8 pfB0 = *(const bf16x8*)&pwB[l16 * 72 + quad * 8];
            bf16x8 pfB1 = *(const bf16x8*)&pwB[l16 * 72 + 32 + quad * 8];
            #pragma unroll
            for (int dt = 0; dt < 4; ++dt) {
                otB[dt] = MFMA16(vf[0][dt], pfB0, otB[dt]);
                otB[dt] = MFMA16(vf[1][dt], pfB1, otB[dt]);
            }
            if (actA) {
                bf16x8 pfA0 = *(const bf16x8*)&pwA[l16 * 72 + quad * 8];
                bf16x8 pfA1 = *(const bf16x8*)&pwA[l16 * 72 + 32 + quad * 8];
                #pragma unroll
                for (int dt = 0; dt < 4; ++dt) {
                    otA[dt] = MFMA16(vf[0][dt], pfA0, otA[dt]);
                    otA[dt] = MFMA16(vf[1][dt], pfA1, otA[dt]);
                }
            }
        }

        // ---- counted-vmcnt sync: drain batch(kc+1), keep batch(kc+2) in flight ----
        asm volatile("s_waitcnt vmcnt(4)" ::: "memory");
        __builtin_amdgcn_s_barrier();
        __builtin_amdgcn_sched_barrier(0);
        cur = (cur + 1 >= 3) ? 0 : cur + 1;
    }
    #undef STAGE_KV

    // ---- l reduction (lanes sharing l16 across quads) + epilogue ----
    laccA += __shfl_xor(laccA, 16);
    laccA += __shfl_xor(laccA, 32);
    laccB += __shfl_xor(laccB, 16);
    laccB += __shfl_xor(laccB, 32);
    const float invA = 1.0f / laccA, invB = 1.0f / laccB;

    #pragma unroll
    for (int dt = 0; dt < 4; ++dt) {
        *(unsigned*)&pwA[l16 * 72 + dt * 16 + quad * 4]     = pk_bf16(otA[dt][0] * invA, otA[dt][1] * invA);
        *(unsigned*)&pwA[l16 * 72 + dt * 16 + quad * 4 + 2] = pk_bf16(otA[dt][2] * invA, otA[dt][3] * invA);
        *(unsigned*)&pwB[l16 * 72 + dt * 16 + quad * 4]     = pk_bf16(otB[dt][0] * invB, otB[dt][1] * invB);
        *(unsigned*)&pwB[l16 * 72 + dt * 16 + quad * 4 + 2] = pk_bf16(otB[dt][2] * invB, otB[dt][3] * invB);
    }
    {
        const int qr = lane >> 2, dc = (lane & 3) * 16;
        bf16x8 a0 = *(const bf16x8*)&pwA[qr * 72 + dc];
        bf16x8 a1 = *(const bf16x8*)&pwA[qr * 72 + dc + 8];
        short* dstA = &comb[(rowbase + q0A + qr) * 1024 + hcol + dc];
        *(bf16x8*)dstA = a0;
        *(bf16x8*)(dstA + 8) = a1;
        bf16x8 b0 = *(const bf16x8*)&pwB[qr * 72 + dc];
        bf16x8 b1 = *(const bf16x8*)&pwB[qr * 72 + dc + 8];
        short* dstB = &comb[(rowbase + q0B + qr) * 1024 + hcol + dc];
        *(bf16x8*)dstB = b0;
        *(bf16x8*)(dstB + 8) = b1;
    }
}

// ---------- launch ----------
extern "C" void kernel_launch(void* const* d_in, const int* in_sizes, int n_in,
                              void* d_out, int out_size, void* d_ws, size_t ws_size,
                              hipStream_t stream)
{
    const float* enc = (const float*)d_in[0];
    const float* Wa  = (const float*)d_in[1];
    const float* ba  = (const float*)d_in[2];
    const float* Wo  = (const float*)d_in[3];
    const float* bo  = (const float*)d_in[4];
    float* out = (float*)d_out;

    // layout (41 MB peak):
    // [0,8)   Abf (dead after gemm1) -> comb
    // [8,10)  WtO    [10,11) biases
    // [11,17) WtA    [17,25) Kx    [25,33) Vx    [33,41) Qw
    char* ws = (char*)d_ws;
    short* Abf  = (short*)ws;
    short* comb = (short*)ws;
    short* WtO  = (short*)(ws + ((size_t)8 << 20));
    short* bbA  = (short*)(ws + ((size_t)10 << 20));
    short* bbO  = (short*)(ws + ((size_t)10 << 20) + 16384);
    short* WtA  = (short*)(ws + ((size_t)11 << 20));
    short* Kx   = (short*)(ws + ((size_t)17 << 20));
    short* Vx   = (short*)(ws + ((size_t)25 << 20));
    short* Qw   = (short*)(ws + ((size_t)33 << 20));

    prep_kernel<<<3074, 256, 0, stream>>>(enc, Wa, ba, Wo, bo, Abf, WtA, bbA, WtO, bbO);
    gemm_bt<128, false, true><<<dim3(24, 32), 256, 0, stream>>>(
        Abf, WtA, bbA, Qw, Kx, Vx, 4096, 3072, 1024);
    attn_kernel<<<dim3(32, 16), 256, 0, stream>>>(Qw, Kx, Vx, comb);
    gemm_bt<64, true, false><<<dim3(16, 32), 256, 0, stream>>>(
        comb, WtO, bbO, out, nullptr, nullptr, 4096, 1024, 1024);
}

// Round 6
// 188.069 us; speedup vs baseline: 1.0102x; 1.0048x over previous
//
#include <hip/hip_runtime.h>
#include <hip/hip_bf16.h>

// ---------- types / helpers ----------
typedef __attribute__((ext_vector_type(8))) short bf16x8;   // 8 bf16 = 4 VGPRs
typedef __attribute__((ext_vector_type(4))) short bf16x4;
typedef __attribute__((ext_vector_type(4))) float f32x4;

__device__ __forceinline__ short f2bf(float f) {
    unsigned u = __float_as_uint(f);
    u += 0x7fff + ((u >> 16) & 1);          // round-to-nearest-even
    return (short)(u >> 16);
}
__device__ __forceinline__ float bf2f(short s) {
    return __uint_as_float(((unsigned)(unsigned short)s) << 16);
}
__device__ __forceinline__ unsigned pk_bf16(float lo, float hi) {
    __hip_bfloat162 t = __float22bfloat162_rn(make_float2(lo, hi));
    unsigned u;
    __builtin_memcpy(&u, &t, 4);
    return u;
}

#define GLOAD_LDS16(gp, lp)                                                            \
    __builtin_amdgcn_global_load_lds(                                                  \
        (const __attribute__((address_space(1))) unsigned*)(gp),                       \
        (__attribute__((address_space(3))) unsigned*)(lp), 16, 0, 0)

#define QK_SCALE 0.180336879f   // (1/sqrt(64)) * log2(e), folded into q at GEMM1
#define MFMA16(a, b, c) __builtin_amdgcn_mfma_f32_16x16x32_bf16((a), (b), (c), 0, 0, 0)

// ---------- fused prep: enc->bf16, biases->bf16, Wa/Wo -> transposed bf16 ----------
__device__ __forceinline__ void tcvt_tile(const float* __restrict__ W, short* __restrict__ Wt,
                                          int K, int N, int bx, int by, int t,
                                          short (*tile)[72]) {
    const int k0 = by * 64, n0 = bx * 64;
    #pragma unroll
    for (int jj = 0; jj < 4; ++jj) {
        int row = jj * 16 + (t >> 4);
        int col = (t & 15) * 4;
        f32x4 v = *(const f32x4*)&W[(size_t)(k0 + row) * N + n0 + col];
        bf16x4 b = {f2bf(v.x), f2bf(v.y), f2bf(v.z), f2bf(v.w)};
        *(bf16x4*)&tile[row][col] = b;
    }
    __syncthreads();
    const int nr = t >> 2, kc = (t & 3) * 16;
    bf16x8 o0, o1;
    #pragma unroll
    for (int j = 0; j < 8; ++j) { o0[j] = tile[kc + j][nr]; o1[j] = tile[kc + 8 + j][nr]; }
    short* dst = &Wt[(size_t)(n0 + nr) * K + k0 + kc];
    *(bf16x8*)dst = o0;
    *(bf16x8*)(dst + 8) = o1;
}

__global__ __launch_bounds__(256) void prep_kernel(
    const float* __restrict__ enc, const float* __restrict__ Wa,
    const float* __restrict__ ba, const float* __restrict__ Wo,
    const float* __restrict__ bo, short* __restrict__ Abf,
    short* __restrict__ WtA, short* __restrict__ bbA,
    short* __restrict__ WtO, short* __restrict__ bbO)
{
    __shared__ alignas(16) short tile[64][72];
    const int id = blockIdx.x, t = threadIdx.x;
    if (id < 2048) {
        const int i = id * 2048 + t * 8;
        f32x4 a = *(const f32x4*)&enc[i];
        f32x4 b = *(const f32x4*)&enc[i + 4];
        bf16x8 o = {f2bf(a.x), f2bf(a.y), f2bf(a.z), f2bf(a.w),
                    f2bf(b.x), f2bf(b.y), f2bf(b.z), f2bf(b.w)};
        *(bf16x8*)&Abf[i] = o;
    } else if (id == 2048) {
        for (int j = t * 8; j < 3072; j += 2048) {
            f32x4 a = *(const f32x4*)&ba[j];
            f32x4 b = *(const f32x4*)&ba[j + 4];
            bf16x8 o = {f2bf(a.x), f2bf(a.y), f2bf(a.z), f2bf(a.w),
                        f2bf(b.x), f2bf(b.y), f2bf(b.z), f2bf(b.w)};
            *(bf16x8*)&bbA[j] = o;
        }
    } else if (id == 2049) {
        if (t < 128) {
            const int j = t * 8;
            f32x4 a = *(const f32x4*)&bo[j];
            f32x4 b = *(const f32x4*)&bo[j + 4];
            bf16x8 o = {f2bf(a.x), f2bf(a.y), f2bf(a.z), f2bf(a.w),
                        f2bf(b.x), f2bf(b.y), f2bf(b.z), f2bf(b.w)};
            *(bf16x8*)&bbO[j] = o;
        }
        __syncthreads();
    } else if (id < 2818) {
        const int lid = id - 2050;
        tcvt_tile(Wa, WtA, 1024, 3072, lid % 48, lid / 48, t, tile);
    } else {
        const int lid = id - 2818;
        tcvt_tile(Wo, WtO, 1024, 1024, lid % 16, lid / 16, t, tile);
    }
}

// ---------- BT GEMM, BK=64: C = A @ Bt^T + bias ----------
// BK=64 halves the barrier-drain count. 16B chunks XOR-swizzled by row
// (chunk ^= row&7): global source pre-swizzled per lane, ds_read applies the
// same XOR. SPLIT3 epilogue (fragment-order coalesced Kx/Vx/Q writeout)
// reuses the As+Bs LDS as the 128x128 Ct buffer -> total LDS 32KB.
// Round-6: Vx key order PERMUTED so attn's QK accumulator IS the PV
// B-operand: slot (f,quad,j) holds physical key f*32+(j>>2)*16+quad*4+(j&3).
// (MFMA k-dim is a reduction index; A/B only need the SAME key order.)
template<int BN, bool F32OUT, bool SPLIT3>
__global__ __launch_bounds__(256) void gemm_bt(
    const short* __restrict__ A, const short* __restrict__ Bt,
    const short* __restrict__ bias, void* __restrict__ C,
    short* __restrict__ Kw, short* __restrict__ Vw, int M, int N, int K)
{
    __shared__ alignas(16) short LB[128 * 64 + BN * 64];
    short* As = LB;                  // [128][64] shorts, 16B chunks row-XOR-swizzled
    short* Bs = LB + 128 * 64;       // [BN][64]
    short* Ct = LB;                  // SPLIT3 epilogue: [128][128] (exactly 32KB)

    const int tid = threadIdx.x, w = tid >> 6, lane = tid & 63;
    const int quad = lane >> 4, l16 = lane & 15;
    constexpr int MT = (BN == 128) ? 4 : 2;
    const int wm = (BN == 128) ? (w >> 1) : w;
    const int wn = (BN == 128) ? (w & 1) : 0;
    const int m0 = blockIdx.y * 128, n0 = blockIdx.x * BN;
    // staging: one gload16 = 64 lanes x 16B = 8 rows x 128B
    const int srow = lane >> 3;                 // 0..7 within the 8-row chunk
    const int scol = ((lane & 7) ^ srow) * 8;   // pre-swizzled source chunk

    f32x4 acc[MT][4] = {};

    for (int k0 = 0; k0 < K; k0 += 64) {
        __syncthreads();
        #pragma unroll
        for (int jj = 0; jj < 4; ++jj) {
            const int rb = w * 32 + jj * 8;
            GLOAD_LDS16(&A[(size_t)(m0 + rb + srow) * K + k0 + scol], &As[rb * 64]);
        }
        if (BN == 128) {
            #pragma unroll
            for (int jj = 0; jj < 4; ++jj) {
                const int rb = w * 32 + jj * 8;
                GLOAD_LDS16(&Bt[(size_t)(n0 + rb + srow) * K + k0 + scol], &Bs[rb * 64]);
            }
        } else {
            #pragma unroll
            for (int jj = 0; jj < 2; ++jj) {
                const int rb = w * 16 + jj * 8;
                GLOAD_LDS16(&Bt[(size_t)(n0 + rb + srow) * K + k0 + scol], &Bs[rb * 64]);
            }
        }
        __syncthreads();
        #pragma unroll
        for (int half = 0; half < 2; ++half) {
            const int kc2 = half * 4 + quad;    // 16B chunk index 0..7
            bf16x8 af[MT], bfr[4];
            #pragma unroll
            for (int i = 0; i < MT; ++i) {
                const int row = wm * (MT * 16) + i * 16 + l16;
                af[i] = *(const bf16x8*)&As[row * 64 + ((kc2 ^ (row & 7)) << 3)];
            }
            #pragma unroll
            for (int i = 0; i < 4; ++i) {
                const int row = wn * 64 + i * 16 + l16;
                bfr[i] = *(const bf16x8*)&Bs[row * 64 + ((kc2 ^ (row & 7)) << 3)];
            }
            #pragma unroll
            for (int mt = 0; mt < MT; ++mt)
                #pragma unroll
                for (int nt = 0; nt < 4; ++nt)
                    acc[mt][nt] = MFMA16(af[mt], bfr[nt], acc[mt][nt]);
        }
    }

    if (SPLIT3) {
        const int g = n0 >> 10;                     // 0=q,1=k,2=v (block-uniform)
        const int lc0 = n0 & 1023;
        __syncthreads();                            // done reading As/Bs; reuse as Ct
        // ---- stage 128x128 C tile into LDS, 16B-chunk XOR swizzle ----
        if (g < 2) {
            // row-major: Ct[row][((col>>3) ^ (row&15))*8 + (col&7)]
            #pragma unroll
            for (int nt = 0; nt < 4; ++nt) {
                const int col = wn * 64 + nt * 16 + l16;
                const float bv = bf2f(bias[n0 + col]);
                const int chunk = col >> 3, wi = col & 7;
                #pragma unroll
                for (int mt = 0; mt < 4; ++mt) {
                    const int rbase = wm * 64 + mt * 16 + quad * 4;
                    #pragma unroll
                    for (int r = 0; r < 4; ++r) {
                        const int row = rbase + r;
                        float v = acc[mt][nt][r] + bv;
                        if (g == 0) v *= QK_SCALE;
                        Ct[row * 128 + (((chunk ^ (row & 15)) << 3) | wi)] = f2bf(v);
                    }
                }
            }
        } else {
            // transposed [d][key]: Ct[d][((key>>3) ^ (d&15))*8 + (key&7)],
            // 4 contiguous keys per acc reg quad -> one 8B store
            #pragma unroll
            for (int nt = 0; nt < 4; ++nt) {
                const int d = wn * 64 + nt * 16 + l16;
                const float bv = bf2f(bias[n0 + d]);
                const int dsw = d & 15;
                #pragma unroll
                for (int mt = 0; mt < 4; ++mt) {
                    const int key0 = wm * 64 + mt * 16 + quad * 4;
                    bf16x4 p = {f2bf(acc[mt][nt][0] + bv), f2bf(acc[mt][nt][1] + bv),
                                f2bf(acc[mt][nt][2] + bv), f2bf(acc[mt][nt][3] + bv)};
                    *(bf16x4*)&Ct[d * 128 + ((((key0 >> 3) ^ dsw) << 3) | (key0 & 7))] = p;
                }
            }
        }
        __syncthreads();
        // ---- coalesced writeout ----
        const int batch = m0 >> 11;
        const int kc0 = (m0 & 2047) >> 6;           // even; tile covers kc0, kc0+1
        const int head0 = lc0 >> 6;                 // even; tile covers head0, head0+1
        if (g == 0) {
            short* dst = (short*)C;                 // Qw, row-major [4096][1024]
            #pragma unroll
            for (int i = 0; i < 8; ++i) {
                const int idx = i * 256 + tid;      // 0..2047
                const int row = idx >> 4, chunk = idx & 15;
                bf16x8 v = *(const bf16x8*)&Ct[row * 128 + ((chunk ^ (row & 15)) << 3)];
                *(bf16x8*)&dst[(size_t)(m0 + row) * 1024 + lc0 + chunk * 8] = v;
            }
        } else if (g == 1) {
            // Kx[bh][kc][c=(s*2+h2)*64+lane][j] = K[kc*64+s*16+l16][h2*32+quad*8+j]
            #pragma unroll
            for (int i = 0; i < 8; ++i) {
                const int idx = i * 256 + tid;
                const int qd = idx >> 9, c = idx & 511;
                const int kcL = qd >> 1, headL = qd & 1;
                const int s = c >> 7, h2 = (c >> 6) & 1;
                const int l16c = c & 15, quadc = (c >> 4) & 3;
                const int row = kcL * 64 + s * 16 + l16c;
                const int colc = headL * 8 + h2 * 4 + quadc;
                bf16x8 v = *(const bf16x8*)&Ct[row * 128 + ((colc ^ (row & 15)) << 3)];
                const int bh = batch * 16 + head0 + headL, kc = kc0 + kcL;
                *(bf16x8*)&Kw[((size_t)(bh * 32 + kc) * 512 + c) * 8] = v;
            }
        } else {
            // Vx[bh][kc][c=(h2*4+dt)*64+lane][j] = V[key][dt*16+l16] with the
            // PERMUTED key = kcL*64 + h2*32 + (j>>2)*16 + quadc*4 + (j&3):
            // j=0..3 -> keys Ka..Ka+3, j=4..7 -> keys Ka+16..Ka+19.
            #pragma unroll
            for (int i = 0; i < 8; ++i) {
                const int idx = i * 256 + tid;
                const int qd = idx >> 9, c = idx & 511;
                const int kcL = qd >> 1, headL = qd & 1;
                const int h2 = c >> 8, dt = (c >> 6) & 3;
                const int l16c = c & 15, quadc = (c >> 4) & 3;
                const int d = headL * 64 + dt * 16 + l16c;
                const int Ka = kcL * 64 + h2 * 32 + quadc * 4;
                const int Kb = Ka + 16;
                bf16x4 va = *(const bf16x4*)&Ct[d * 128 + (((Ka >> 3) ^ (d & 15)) << 3) + (Ka & 7)];
                bf16x4 vb = *(const bf16x4*)&Ct[d * 128 + (((Kb >> 3) ^ (d & 15)) << 3) + (Kb & 7)];
                bf16x8 v = {va[0], va[1], va[2], va[3], vb[0], vb[1], vb[2], vb[3]};
                const int bh = batch * 16 + head0 + headL, kc = kc0 + kcL;
                *(bf16x8*)&Vw[((size_t)(bh * 32 + kc) * 512 + c) * 8] = v;
            }
        }
    } else {
        #pragma unroll
        for (int nt = 0; nt < 4; ++nt) {
            const int col = n0 + wn * 64 + nt * 16 + l16;
            const float bv = bf2f(bias[col]);
            #pragma unroll
            for (int mt = 0; mt < MT; ++mt) {
                const int row = m0 + wm * (MT * 16) + mt * 16 + quad * 4;
                #pragma unroll
                for (int r = 0; r < 4; ++r) {
                    float v = acc[mt][nt][r] + bv;
                    if (F32OUT) ((float*)C)[(size_t)(row + r) * N + col] = v;
                    else        ((short*)C)[(size_t)(row + r) * N + col] = f2bf(v);
                }
            }
        }
    }
}

// ---------- causal flash attention: LDS-staged K/V, counted-vmcnt pipeline ----------
// Round-6: P never touches LDS. The QK accumulator layout (key = s*16+quad*4+r,
// q = l16) is consumed DIRECTLY as the PV B-operand because Vx's key order is
// permuted to match (see gemm epilogue): pf[f] = {pk(sv[2f][0,1]),
// pk(sv[2f][2,3]), pk(sv[2f+1][0,1]), pk(sv[2f+1][2,3])}. Removes 12-24
// ds-ops + two LDS write->read round-trips from every step's critical path.
__global__ __launch_bounds__(256) void attn_kernel(
    const short* __restrict__ Qw, const short* __restrict__ Kx,
    const short* __restrict__ Vx, short* __restrict__ comb)
{
    __shared__ alignas(16) short KV[3][2][4096];      // [buf][K/V][tile] 48KB
    __shared__ alignas(16) short Ps[4][2][16 * 72];   // [wave][tile A/B] epilogue only

    const int tid = threadIdx.x, w4 = tid >> 6, lane = tid & 63;
    const int p = w4 >> 1;         // pair index within block
    const int w = w4 & 1;          // 16-row q sub-tile within the 32-row tiles
    const int quad = lane >> 4, l16 = lane & 15;
    const int bh = blockIdx.x;
    const int g = blockIdx.y;                       // 0..15
    const int tA = 2 * g + p, tB = 63 - tA;
    const int batch = bh >> 4, head = bh & 15;
    const size_t rowbase = (size_t)batch * 2048;
    const int hcol = head * 64;
    const int q0A = tA * 32 + w * 16, q0B = tB * 32 + w * 16;
    const int diagA = g;                            // tA>>1 for both p
    const int maxD = 31 - g;                        // tB>>1 for both p
    const short* Kxbh = Kx + (size_t)bh * 131072;
    const short* Vxbh = Vx + (size_t)bh * 131072;
    const int lofs = lane * 8;
    short* pwA = &Ps[w4][0][0];
    short* pwB = &Ps[w4][1][0];

    // Q fragments (B-operand: q = l16, d = quad*8+j (+32))
    bf16x8 qfA[2], qfB[2];
    {
        const short* pa = &Qw[(rowbase + q0A + l16) * 1024 + hcol];
        const short* pb = &Qw[(rowbase + q0B + l16) * 1024 + hcol];
        qfA[0] = *(const bf16x8*)(pa + quad * 8);
        qfA[1] = *(const bf16x8*)(pa + 32 + quad * 8);
        qfB[0] = *(const bf16x8*)(pb + quad * 8);
        qfB[1] = *(const bf16x8*)(pb + 32 + quad * 8);
    }
    // drain Q loads so in-loop vmcnt counts are statically exact
    asm volatile("s_waitcnt vmcnt(0)" ::: "memory");

    f32x4 otA[4] = {}, otB[4] = {};
    float laccA = 0.f, laccB = 0.f;

    // per-wave staging slice: wave w4 stages chunks {j*256 + w4*64 + lane}
    const int sbase = w4 * 64;

    // stage(kcs, buf): 4 global_load_lds (2 K + 2 V), 16KB/block-step total
    #define STAGE_KV(kcs, buf)                                                              \
        do {                                                                                \
            const size_t nb_ = (size_t)(kcs)*4096;                                          \
            _Pragma("unroll")                                                               \
            for (int j = 0; j < 2; ++j) {                                                   \
                GLOAD_LDS16(&Kxbh[nb_ + (size_t)(j * 256 + sbase + lane) * 8],              \
                            &KV[buf][0][(j * 256 + sbase) * 8]);                            \
                GLOAD_LDS16(&Vxbh[nb_ + (size_t)(j * 256 + sbase + lane) * 8],              \
                            &KV[buf][1][(j * 256 + sbase) * 8]);                            \
            }                                                                               \
        } while (0)

    // prologue: stage kc=0 -> buf0, kc=1 -> buf1 (maxD >= 16, always valid)
    STAGE_KV(0, 0);
    STAGE_KV(1, 1);
    asm volatile("s_waitcnt vmcnt(4)" ::: "memory");   // drain batch(0), keep batch(1)
    __builtin_amdgcn_s_barrier();
    __builtin_amdgcn_sched_barrier(0);

    int cur = 0;
    for (int kc = 0; kc <= maxD; ++kc) {
        const bool actA = (kc <= diagA);
        const int key0 = kc * 64;

        // ---- issue batch(kc+2) into buf (kc+2)%3 (clamped: uniform 4 loads/step) ----
        {
            const int ks = (kc + 2 <= maxD) ? kc + 2 : maxD;
            const int wb = (cur + 2 >= 3) ? cur - 1 : cur + 2;
            STAGE_KV(ks, wb);
        }

        // ---- K fragments from LDS ----
        bf16x8 kf[4][2];
        #pragma unroll
        for (int s = 0; s < 4; ++s) {
            kf[s][0] = *(const bf16x8*)&KV[cur][0][(s * 2 + 0) * 512 + lofs];
            kf[s][1] = *(const bf16x8*)&KV[cur][0][(s * 2 + 1) * 512 + lofs];
        }

        // ---- QK (S^T = K.Q^T) ----
        f32x4 svA[4], svB[4];
        #pragma unroll
        for (int s = 0; s < 4; ++s) {
            f32x4 a = {0.f, 0.f, 0.f, 0.f};
            a = MFMA16(kf[s][0], qfB[0], a);
            a = MFMA16(kf[s][1], qfB[1], a);
            svB[s] = a;
            if (actA) {
                f32x4 b = {0.f, 0.f, 0.f, 0.f};
                b = MFMA16(kf[s][0], qfA[0], b);
                b = MFMA16(kf[s][1], qfA[1], b);
                svA[s] = b;
            }
        }

        // ---- V fragments from LDS (key-permuted layout; lgkm hides under softmax) ----
        bf16x8 vf[2][4];
        #pragma unroll
        for (int hh = 0; hh < 2; ++hh)
            #pragma unroll
            for (int dt = 0; dt < 4; ++dt)
                vf[hh][dt] = *(const bf16x8*)&KV[cur][1][(hh * 4 + dt) * 512 + lofs];

        // ---- tile B: mask -> exp2 -> pack in-register -> PV ----
        if (kc == maxD) {
            const int qq = q0B + l16;
            #pragma unroll
            for (int s = 0; s < 4; ++s) {
                const int keyb = key0 + s * 16 + quad * 4;
                #pragma unroll
                for (int r = 0; r < 4; ++r)
                    svB[s][r] = (keyb + r <= qq) ? svB[s][r] : -1e30f;
            }
        }
        {
            unsigned uB[4][2];
            #pragma unroll
            for (int s = 0; s < 4; ++s) {
                #pragma unroll
                for (int r = 0; r < 4; ++r) svB[s][r] = exp2f(svB[s][r]);
                laccB += (svB[s][0] + svB[s][1]) + (svB[s][2] + svB[s][3]);
                uB[s][0] = pk_bf16(svB[s][0], svB[s][1]);
                uB[s][1] = pk_bf16(svB[s][2], svB[s][3]);
            }
            bf16x8 pfB0, pfB1;
            {
                unsigned t0[4] = {uB[0][0], uB[0][1], uB[1][0], uB[1][1]};
                unsigned t1[4] = {uB[2][0], uB[2][1], uB[3][0], uB[3][1]};
                __builtin_memcpy(&pfB0, t0, 16);
                __builtin_memcpy(&pfB1, t1, 16);
            }
            #pragma unroll
            for (int dt = 0; dt < 4; ++dt) {
                otB[dt] = MFMA16(vf[0][dt], pfB0, otB[dt]);
                otB[dt] = MFMA16(vf[1][dt], pfB1, otB[dt]);
            }
        }

        // ---- tile A (when active): same path ----
        if (actA) {
            if (kc == diagA) {
                const int qq = q0A + l16;
                #pragma unroll
                for (int s = 0; s < 4; ++s) {
                    const int keyb = key0 + s * 16 + quad * 4;
                    #pragma unroll
                    for (int r = 0; r < 4; ++r)
                        svA[s][r] = (keyb + r <= qq) ? svA[s][r] : -1e30f;
                }
            }
            unsigned uA[4][2];
            #pragma unroll
            for (int s = 0; s < 4; ++s) {
                #pragma unroll
                for (int r = 0; r < 4; ++r) svA[s][r] = exp2f(svA[s][r]);
                laccA += (svA[s][0] + svA[s][1]) + (svA[s][2] + svA[s][3]);
                uA[s][0] = pk_bf16(svA[s][0], svA[s][1]);
                uA[s][1] = pk_bf16(svA[s][2], svA[s][3]);
            }
            bf16x8 pfA0, pfA1;
            {
                unsigned t0[4] = {uA[0][0], uA[0][1], uA[1][0], uA[1][1]};
                unsigned t1[4] = {uA[2][0], uA[2][1], uA[3][0], uA[3][1]};
                __builtin_memcpy(&pfA0, t0, 16);
                __builtin_memcpy(&pfA1, t1, 16);
            }
            #pragma unroll
            for (int dt = 0; dt < 4; ++dt) {
                otA[dt] = MFMA16(vf[0][dt], pfA0, otA[dt]);
                otA[dt] = MFMA16(vf[1][dt], pfA1, otA[dt]);
            }
        }

        // ---- counted-vmcnt sync: drain batch(kc+1), keep batch(kc+2) in flight ----
        asm volatile("s_waitcnt vmcnt(4)" ::: "memory");
        __builtin_amdgcn_s_barrier();
        __builtin_amdgcn_sched_barrier(0);
        cur = (cur + 1 >= 3) ? 0 : cur + 1;
    }
    #undef STAGE_KV

    // ---- l reduction (lanes sharing l16 across quads) + epilogue ----
    laccA += __shfl_xor(laccA, 16);
    laccA += __shfl_xor(laccA, 32);
    laccB += __shfl_xor(laccB, 16);
    laccB += __shfl_xor(laccB, 32);
    const float invA = 1.0f / laccA, invB = 1.0f / laccB;

    #pragma unroll
    for (int dt = 0; dt < 4; ++dt) {
        *(unsigned*)&pwA[l16 * 72 + dt * 16 + quad * 4]     = pk_bf16(otA[dt][0] * invA, otA[dt][1] * invA);
        *(unsigned*)&pwA[l16 * 72 + dt * 16 + quad * 4 + 2] = pk_bf16(otA[dt][2] * invA, otA[dt][3] * invA);
        *(unsigned*)&pwB[l16 * 72 + dt * 16 + quad * 4]     = pk_bf16(otB[dt][0] * invB, otB[dt][1] * invB);
        *(unsigned*)&pwB[l16 * 72 + dt * 16 + quad * 4 + 2] = pk_bf16(otB[dt][2] * invB, otB[dt][3] * invB);
    }
    {
        const int qr = lane >> 2, dc = (lane & 3) * 16;
        bf16x8 a0 = *(const bf16x8*)&pwA[qr * 72 + dc];
        bf16x8 a1 = *(const bf16x8*)&pwA[qr * 72 + dc + 8];
        short* dstA = &comb[(rowbase + q0A + qr) * 1024 + hcol + dc];
        *(bf16x8*)dstA = a0;
        *(bf16x8*)(dstA + 8) = a1;
        bf16x8 b0 = *(const bf16x8*)&pwB[qr * 72 + dc];
        bf16x8 b1 = *(const bf16x8*)&pwB[qr * 72 + dc + 8];
        short* dstB = &comb[(rowbase + q0B + qr) * 1024 + hcol + dc];
        *(bf16x8*)dstB = b0;
        *(bf16x8*)(dstB + 8) = b1;
    }
}

// ---------- launch ----------
extern "C" void kernel_launch(void* const* d_in, const int* in_sizes, int n_in,
                              void* d_out, int out_size, void* d_ws, size_t ws_size,
                              hipStream_t stream)
{
    const float* enc = (const float*)d_in[0];
    const float* Wa  = (const float*)d_in[1];
    const float* ba  = (const float*)d_in[2];
    const float* Wo  = (const float*)d_in[3];
    const float* bo  = (const float*)d_in[4];
    float* out = (float*)d_out;

    // layout (41 MB peak):
    // [0,8)   Abf (dead after gemm1) -> comb
    // [8,10)  WtO    [10,11) biases
    // [11,17) WtA    [17,25) Kx    [25,33) Vx    [33,41) Qw
    char* ws = (char*)d_ws;
    short* Abf  = (short*)ws;
    short* comb = (short*)ws;
    short* WtO  = (short*)(ws + ((size_t)8 << 20));
    short* bbA  = (short*)(ws + ((size_t)10 << 20));
    short* bbO  = (short*)(ws + ((size_t)10 << 20) + 16384);
    short* WtA  = (short*)(ws + ((size_t)11 << 20));
    short* Kx   = (short*)(ws + ((size_t)17 << 20));
    short* Vx   = (short*)(ws + ((size_t)25 << 20));
    short* Qw   = (short*)(ws + ((size_t)33 << 20));

    prep_kernel<<<3074, 256, 0, stream>>>(enc, Wa, ba, Wo, bo, Abf, WtA, bbA, WtO, bbO);
    gemm_bt<128, false, true><<<dim3(24, 32), 256, 0, stream>>>(
        Abf, WtA, bbA, Qw, Kx, Vx, 4096, 3072, 1024);
    attn_kernel<<<dim3(32, 16), 256, 0, stream>>>(Qw, Kx, Vx, comb);
    gemm_bt<64, true, false><<<dim3(16, 32), 256, 0, stream>>>(
        comb, WtO, bbO, out, nullptr, nullptr, 4096, 1024, 1024);
}

// Round 7
// 178.430 us; speedup vs baseline: 1.0647x; 1.0540x over previous
//
#include <hip/hip_runtime.h>
#include <hip/hip_bf16.h>

// ---------- types / helpers ----------
typedef __attribute__((ext_vector_type(8))) short bf16x8;   // 8 bf16 = 4 VGPRs
typedef __attribute__((ext_vector_type(4))) short bf16x4;
typedef __attribute__((ext_vector_type(4))) float f32x4;

__device__ __forceinline__ short f2bf(float f) {
    unsigned u = __float_as_uint(f);
    u += 0x7fff + ((u >> 16) & 1);          // round-to-nearest-even
    return (short)(u >> 16);
}
__device__ __forceinline__ float bf2f(short s) {
    return __uint_as_float(((unsigned)(unsigned short)s) << 16);
}
__device__ __forceinline__ unsigned pk_bf16(float lo, float hi) {
    __hip_bfloat162 t = __float22bfloat162_rn(make_float2(lo, hi));
    unsigned u;
    __builtin_memcpy(&u, &t, 4);
    return u;
}

#define GLOAD_LDS16(gp, lp)                                                            \
    __builtin_amdgcn_global_load_lds(                                                  \
        (const __attribute__((address_space(1))) unsigned*)(gp),                       \
        (__attribute__((address_space(3))) unsigned*)(lp), 16, 0, 0)

#define QK_SCALE 0.180336879f   // (1/sqrt(64)) * log2(e), folded into q at GEMM1
#define MFMA16(a, b, c) __builtin_amdgcn_mfma_f32_16x16x32_bf16((a), (b), (c), 0, 0, 0)

// ---------- fused prep: enc->bf16, biases->bf16, Wa/Wo -> transposed bf16 ----------
__device__ __forceinline__ void tcvt_tile(const float* __restrict__ W, short* __restrict__ Wt,
                                          int K, int N, int bx, int by, int t,
                                          short (*tile)[72]) {
    const int k0 = by * 64, n0 = bx * 64;
    #pragma unroll
    for (int jj = 0; jj < 4; ++jj) {
        int row = jj * 16 + (t >> 4);
        int col = (t & 15) * 4;
        f32x4 v = *(const f32x4*)&W[(size_t)(k0 + row) * N + n0 + col];
        bf16x4 b = {f2bf(v.x), f2bf(v.y), f2bf(v.z), f2bf(v.w)};
        *(bf16x4*)&tile[row][col] = b;
    }
    __syncthreads();
    const int nr = t >> 2, kc = (t & 3) * 16;
    bf16x8 o0, o1;
    #pragma unroll
    for (int j = 0; j < 8; ++j) { o0[j] = tile[kc + j][nr]; o1[j] = tile[kc + 8 + j][nr]; }
    short* dst = &Wt[(size_t)(n0 + nr) * K + k0 + kc];
    *(bf16x8*)dst = o0;
    *(bf16x8*)(dst + 8) = o1;
}

__global__ __launch_bounds__(256) void prep_kernel(
    const float* __restrict__ enc, const float* __restrict__ Wa,
    const float* __restrict__ ba, const float* __restrict__ Wo,
    const float* __restrict__ bo, short* __restrict__ Abf,
    short* __restrict__ WtA, short* __restrict__ bbA,
    short* __restrict__ WtO, short* __restrict__ bbO)
{
    __shared__ alignas(16) short tile[64][72];
    const int id = blockIdx.x, t = threadIdx.x;
    if (id < 2048) {
        const int i = id * 2048 + t * 8;
        f32x4 a = *(const f32x4*)&enc[i];
        f32x4 b = *(const f32x4*)&enc[i + 4];
        bf16x8 o = {f2bf(a.x), f2bf(a.y), f2bf(a.z), f2bf(a.w),
                    f2bf(b.x), f2bf(b.y), f2bf(b.z), f2bf(b.w)};
        *(bf16x8*)&Abf[i] = o;
    } else if (id == 2048) {
        for (int j = t * 8; j < 3072; j += 2048) {
            f32x4 a = *(const f32x4*)&ba[j];
            f32x4 b = *(const f32x4*)&ba[j + 4];
            bf16x8 o = {f2bf(a.x), f2bf(a.y), f2bf(a.z), f2bf(a.w),
                        f2bf(b.x), f2bf(b.y), f2bf(b.z), f2bf(b.w)};
            *(bf16x8*)&bbA[j] = o;
        }
    } else if (id == 2049) {
        if (t < 128) {
            const int j = t * 8;
            f32x4 a = *(const f32x4*)&bo[j];
            f32x4 b = *(const f32x4*)&bo[j + 4];
            bf16x8 o = {f2bf(a.x), f2bf(a.y), f2bf(a.z), f2bf(a.w),
                        f2bf(b.x), f2bf(b.y), f2bf(b.z), f2bf(b.w)};
            *(bf16x8*)&bbO[j] = o;
        }
        __syncthreads();
    } else if (id < 2818) {
        const int lid = id - 2050;
        tcvt_tile(Wa, WtA, 1024, 3072, lid % 48, lid / 48, t, tile);
    } else {
        const int lid = id - 2818;
        tcvt_tile(Wo, WtO, 1024, 1024, lid % 16, lid / 16, t, tile);
    }
}

// ---------- BT GEMM, BK=64: C = A @ Bt^T + bias ----------
// BK=64 halves the barrier-drain count. 16B chunks XOR-swizzled by row
// (chunk ^= row&7): global source pre-swizzled per lane, ds_read applies the
// same XOR. SPLIT3 epilogue (fragment-order coalesced Kx/Vx/Q writeout)
// reuses the As+Bs LDS as the 128x128 Ct buffer -> total LDS 32KB.
// Vx key order PERMUTED so attn's QK accumulator IS the PV B-operand:
// slot (f,quad,j) holds physical key f*32+(j>>2)*16+quad*4+(j&3).
template<int BN, bool F32OUT, bool SPLIT3>
__global__ __launch_bounds__(256) void gemm_bt(
    const short* __restrict__ A, const short* __restrict__ Bt,
    const short* __restrict__ bias, void* __restrict__ C,
    short* __restrict__ Kw, short* __restrict__ Vw, int M, int N, int K)
{
    __shared__ alignas(16) short LB[128 * 64 + BN * 64];
    short* As = LB;                  // [128][64] shorts, 16B chunks row-XOR-swizzled
    short* Bs = LB + 128 * 64;       // [BN][64]
    short* Ct = LB;                  // SPLIT3 epilogue: [128][128] (exactly 32KB)

    const int tid = threadIdx.x, w = tid >> 6, lane = tid & 63;
    const int quad = lane >> 4, l16 = lane & 15;
    constexpr int MT = (BN == 128) ? 4 : 2;
    const int wm = (BN == 128) ? (w >> 1) : w;
    const int wn = (BN == 128) ? (w & 1) : 0;
    const int m0 = blockIdx.y * 128, n0 = blockIdx.x * BN;
    // staging: one gload16 = 64 lanes x 16B = 8 rows x 128B
    const int srow = lane >> 3;                 // 0..7 within the 8-row chunk
    const int scol = ((lane & 7) ^ srow) * 8;   // pre-swizzled source chunk

    f32x4 acc[MT][4] = {};

    for (int k0 = 0; k0 < K; k0 += 64) {
        __syncthreads();
        #pragma unroll
        for (int jj = 0; jj < 4; ++jj) {
            const int rb = w * 32 + jj * 8;
            GLOAD_LDS16(&A[(size_t)(m0 + rb + srow) * K + k0 + scol], &As[rb * 64]);
        }
        if (BN == 128) {
            #pragma unroll
            for (int jj = 0; jj < 4; ++jj) {
                const int rb = w * 32 + jj * 8;
                GLOAD_LDS16(&Bt[(size_t)(n0 + rb + srow) * K + k0 + scol], &Bs[rb * 64]);
            }
        } else {
            #pragma unroll
            for (int jj = 0; jj < 2; ++jj) {
                const int rb = w * 16 + jj * 8;
                GLOAD_LDS16(&Bt[(size_t)(n0 + rb + srow) * K + k0 + scol], &Bs[rb * 64]);
            }
        }
        __syncthreads();
        #pragma unroll
        for (int half = 0; half < 2; ++half) {
            const int kc2 = half * 4 + quad;    // 16B chunk index 0..7
            bf16x8 af[MT], bfr[4];
            #pragma unroll
            for (int i = 0; i < MT; ++i) {
                const int row = wm * (MT * 16) + i * 16 + l16;
                af[i] = *(const bf16x8*)&As[row * 64 + ((kc2 ^ (row & 7)) << 3)];
            }
            #pragma unroll
            for (int i = 0; i < 4; ++i) {
                const int row = wn * 64 + i * 16 + l16;
                bfr[i] = *(const bf16x8*)&Bs[row * 64 + ((kc2 ^ (row & 7)) << 3)];
            }
            #pragma unroll
            for (int mt = 0; mt < MT; ++mt)
                #pragma unroll
                for (int nt = 0; nt < 4; ++nt)
                    acc[mt][nt] = MFMA16(af[mt], bfr[nt], acc[mt][nt]);
        }
    }

    if (SPLIT3) {
        const int g = n0 >> 10;                     // 0=q,1=k,2=v (block-uniform)
        const int lc0 = n0 & 1023;
        __syncthreads();                            // done reading As/Bs; reuse as Ct
        // ---- stage 128x128 C tile into LDS, 16B-chunk XOR swizzle ----
        if (g < 2) {
            // row-major: Ct[row][((col>>3) ^ (row&15))*8 + (col&7)]
            #pragma unroll
            for (int nt = 0; nt < 4; ++nt) {
                const int col = wn * 64 + nt * 16 + l16;
                const float bv = bf2f(bias[n0 + col]);
                const int chunk = col >> 3, wi = col & 7;
                #pragma unroll
                for (int mt = 0; mt < 4; ++mt) {
                    const int rbase = wm * 64 + mt * 16 + quad * 4;
                    #pragma unroll
                    for (int r = 0; r < 4; ++r) {
                        const int row = rbase + r;
                        float v = acc[mt][nt][r] + bv;
                        if (g == 0) v *= QK_SCALE;
                        Ct[row * 128 + (((chunk ^ (row & 15)) << 3) | wi)] = f2bf(v);
                    }
                }
            }
        } else {
            // transposed [d][key]: Ct[d][((key>>3) ^ (d&15))*8 + (key&7)],
            // 4 contiguous keys per acc reg quad -> one 8B store
            #pragma unroll
            for (int nt = 0; nt < 4; ++nt) {
                const int d = wn * 64 + nt * 16 + l16;
                const float bv = bf2f(bias[n0 + d]);
                const int dsw = d & 15;
                #pragma unroll
                for (int mt = 0; mt < 4; ++mt) {
                    const int key0 = wm * 64 + mt * 16 + quad * 4;
                    bf16x4 p = {f2bf(acc[mt][nt][0] + bv), f2bf(acc[mt][nt][1] + bv),
                                f2bf(acc[mt][nt][2] + bv), f2bf(acc[mt][nt][3] + bv)};
                    *(bf16x4*)&Ct[d * 128 + ((((key0 >> 3) ^ dsw) << 3) | (key0 & 7))] = p;
                }
            }
        }
        __syncthreads();
        // ---- coalesced writeout ----
        const int batch = m0 >> 11;
        const int kc0 = (m0 & 2047) >> 6;           // even; tile covers kc0, kc0+1
        const int head0 = lc0 >> 6;                 // even; tile covers head0, head0+1
        if (g == 0) {
            short* dst = (short*)C;                 // Qw, row-major [4096][1024]
            #pragma unroll
            for (int i = 0; i < 8; ++i) {
                const int idx = i * 256 + tid;      // 0..2047
                const int row = idx >> 4, chunk = idx & 15;
                bf16x8 v = *(const bf16x8*)&Ct[row * 128 + ((chunk ^ (row & 15)) << 3)];
                *(bf16x8*)&dst[(size_t)(m0 + row) * 1024 + lc0 + chunk * 8] = v;
            }
        } else if (g == 1) {
            // Kx[bh][kc][c=(s*2+h2)*64+lane][j] = K[kc*64+s*16+l16][h2*32+quad*8+j]
            #pragma unroll
            for (int i = 0; i < 8; ++i) {
                const int idx = i * 256 + tid;
                const int qd = idx >> 9, c = idx & 511;
                const int kcL = qd >> 1, headL = qd & 1;
                const int s = c >> 7, h2 = (c >> 6) & 1;
                const int l16c = c & 15, quadc = (c >> 4) & 3;
                const int row = kcL * 64 + s * 16 + l16c;
                const int colc = headL * 8 + h2 * 4 + quadc;
                bf16x8 v = *(const bf16x8*)&Ct[row * 128 + ((colc ^ (row & 15)) << 3)];
                const int bh = batch * 16 + head0 + headL, kc = kc0 + kcL;
                *(bf16x8*)&Kw[((size_t)(bh * 32 + kc) * 512 + c) * 8] = v;
            }
        } else {
            // Vx[bh][kc][c=(h2*4+dt)*64+lane][j] = V[key][dt*16+l16] with the
            // PERMUTED key = kcL*64 + h2*32 + (j>>2)*16 + quadc*4 + (j&3):
            // j=0..3 -> keys Ka..Ka+3, j=4..7 -> keys Ka+16..Ka+19.
            #pragma unroll
            for (int i = 0; i < 8; ++i) {
                const int idx = i * 256 + tid;
                const int qd = idx >> 9, c = idx & 511;
                const int kcL = qd >> 1, headL = qd & 1;
                const int h2 = c >> 8, dt = (c >> 6) & 3;
                const int l16c = c & 15, quadc = (c >> 4) & 3;
                const int d = headL * 64 + dt * 16 + l16c;
                const int Ka = kcL * 64 + h2 * 32 + quadc * 4;
                const int Kb = Ka + 16;
                bf16x4 va = *(const bf16x4*)&Ct[d * 128 + (((Ka >> 3) ^ (d & 15)) << 3) + (Ka & 7)];
                bf16x4 vb = *(const bf16x4*)&Ct[d * 128 + (((Kb >> 3) ^ (d & 15)) << 3) + (Kb & 7)];
                bf16x8 v = {va[0], va[1], va[2], va[3], vb[0], vb[1], vb[2], vb[3]};
                const int bh = batch * 16 + head0 + headL, kc = kc0 + kcL;
                *(bf16x8*)&Vw[((size_t)(bh * 32 + kc) * 512 + c) * 8] = v;
            }
        }
    } else {
        #pragma unroll
        for (int nt = 0; nt < 4; ++nt) {
            const int col = n0 + wn * 64 + nt * 16 + l16;
            const float bv = bf2f(bias[col]);
            #pragma unroll
            for (int mt = 0; mt < MT; ++mt) {
                const int row = m0 + wm * (MT * 16) + mt * 16 + quad * 4;
                #pragma unroll
                for (int r = 0; r < 4; ++r) {
                    float v = acc[mt][nt][r] + bv;
                    if (F32OUT) ((float*)C)[(size_t)(row + r) * N + col] = v;
                    else        ((short*)C)[(size_t)(row + r) * N + col] = f2bf(v);
                }
            }
        }
    }
}

// ---------- causal flash attention: 64-row q-bands, occupancy-first ----------
// Round-7: counters across 5 schedule variants were invariant (per-SIMD VALU
// ~14%, MFMA ~13%, everything idle) => latency-bound at ~1.4 eff waves/SIMD.
// Two structural causes fixed here:
//  (1) LDS 67.6KB gated occupancy at 2 blocks/CU. Ps is now UNIONED into the
//      KV buffer (used only post-loop) -> 48KB -> 3 blocks/CU (+50% waves).
//  (2) {tA,63-tA} pairing left 65% of steps half-idle and walls varying
//      17..32 steps. Now one block = one 64-row band (4 waves x 16 rows),
//      keys kc=0..n: every wave active every step, uniform trip count.
//      Grid 1024 blocks, longest-band-first (n = 31 - blk/32) for makespan.
// Counted-vmcnt triple-buffer staging pipeline unchanged (T3/T4).
__global__ __launch_bounds__(256) void attn_kernel(
    const short* __restrict__ Qw, const short* __restrict__ Kx,
    const short* __restrict__ Vx, short* __restrict__ comb)
{
    __shared__ alignas(16) short KV[3][2][4096];      // 48KB; reused as Ps post-loop

    const int tid = threadIdx.x, w4 = tid >> 6, lane = tid & 63;
    const int quad = lane >> 4, l16 = lane & 15;
    const int blk = blockIdx.x;
    const int n = 31 - (blk >> 5);                  // band index, longest first
    const int bh = blk & 31;
    const int batch = bh >> 4, head = bh & 15;
    const size_t rowbase = (size_t)batch * 2048;
    const int hcol = head * 64;
    const int q0 = n * 64 + w4 * 16;                // this wave's 16 q-rows
    const short* Kxbh = Kx + (size_t)bh * 131072;
    const short* Vxbh = Vx + (size_t)bh * 131072;
    const int lofs = lane * 8;

    // Q fragment (B-operand: q = l16, d = quad*8+j (+32))
    bf16x8 qf[2];
    {
        const short* pq = &Qw[(rowbase + q0 + l16) * 1024 + hcol];
        qf[0] = *(const bf16x8*)(pq + quad * 8);
        qf[1] = *(const bf16x8*)(pq + 32 + quad * 8);
    }
    // drain Q loads so in-loop vmcnt counts are statically exact
    asm volatile("s_waitcnt vmcnt(0)" ::: "memory");

    f32x4 ot[4] = {};
    float lacc = 0.f;

    // per-wave staging slice: wave w4 stages chunks {j*256 + w4*64 + lane}
    const int sbase = w4 * 64;

    #define STAGE_KV(kcs, buf)                                                              \
        do {                                                                                \
            const size_t nb_ = (size_t)(kcs)*4096;                                          \
            _Pragma("unroll")                                                               \
            for (int j = 0; j < 2; ++j) {                                                   \
                GLOAD_LDS16(&Kxbh[nb_ + (size_t)(j * 256 + sbase + lane) * 8],              \
                            &KV[buf][0][(j * 256 + sbase) * 8]);                            \
                GLOAD_LDS16(&Vxbh[nb_ + (size_t)(j * 256 + sbase + lane) * 8],              \
                            &KV[buf][1][(j * 256 + sbase) * 8]);                            \
            }                                                                               \
        } while (0)

    // prologue: stage kc=0 -> buf0, kc=min(1,n) -> buf1
    STAGE_KV(0, 0);
    STAGE_KV((n >= 1) ? 1 : 0, 1);
    asm volatile("s_waitcnt vmcnt(4)" ::: "memory");   // drain batch(0), keep batch(1)
    __builtin_amdgcn_s_barrier();
    __builtin_amdgcn_sched_barrier(0);

    int cur = 0;
    for (int kc = 0; kc <= n; ++kc) {
        // ---- issue batch(kc+2) into buf (kc+2)%3 (clamped: uniform 4 loads/step) ----
        {
            const int ks = (kc + 2 <= n) ? kc + 2 : n;
            const int wb = (cur + 2 >= 3) ? cur - 1 : cur + 2;
            STAGE_KV(ks, wb);
        }

        // ---- K fragments from LDS ----
        bf16x8 kf[4][2];
        #pragma unroll
        for (int s = 0; s < 4; ++s) {
            kf[s][0] = *(const bf16x8*)&KV[cur][0][(s * 2 + 0) * 512 + lofs];
            kf[s][1] = *(const bf16x8*)&KV[cur][0][(s * 2 + 1) * 512 + lofs];
        }

        // ---- QK (S^T = K.Q^T) ----
        f32x4 sv[4];
        #pragma unroll
        for (int s = 0; s < 4; ++s) {
            f32x4 a = {0.f, 0.f, 0.f, 0.f};
            a = MFMA16(kf[s][0], qf[0], a);
            a = MFMA16(kf[s][1], qf[1], a);
            sv[s] = a;
        }

        // ---- V fragments from LDS (key-permuted layout) ----
        bf16x8 vf[2][4];
        #pragma unroll
        for (int hh = 0; hh < 2; ++hh)
            #pragma unroll
            for (int dt = 0; dt < 4; ++dt)
                vf[hh][dt] = *(const bf16x8*)&KV[cur][1][(hh * 4 + dt) * 512 + lofs];

        // ---- mask (last step only) -> exp2 -> pack in-register -> PV ----
        if (kc == n) {
            const int qq = q0 + l16;
            #pragma unroll
            for (int s = 0; s < 4; ++s) {
                const int keyb = kc * 64 + s * 16 + quad * 4;
                #pragma unroll
                for (int r = 0; r < 4; ++r)
                    sv[s][r] = (keyb + r <= qq) ? sv[s][r] : -1e30f;
            }
        }
        {
            unsigned u[4][2];
            #pragma unroll
            for (int s = 0; s < 4; ++s) {
                #pragma unroll
                for (int r = 0; r < 4; ++r) sv[s][r] = exp2f(sv[s][r]);
                lacc += (sv[s][0] + sv[s][1]) + (sv[s][2] + sv[s][3]);
                u[s][0] = pk_bf16(sv[s][0], sv[s][1]);
                u[s][1] = pk_bf16(sv[s][2], sv[s][3]);
            }
            bf16x8 pf0, pf1;
            {
                unsigned t0[4] = {u[0][0], u[0][1], u[1][0], u[1][1]};
                unsigned t1[4] = {u[2][0], u[2][1], u[3][0], u[3][1]};
                __builtin_memcpy(&pf0, t0, 16);
                __builtin_memcpy(&pf1, t1, 16);
            }
            #pragma unroll
            for (int dt = 0; dt < 4; ++dt) {
                ot[dt] = MFMA16(vf[0][dt], pf0, ot[dt]);
                ot[dt] = MFMA16(vf[1][dt], pf1, ot[dt]);
            }
        }

        // ---- counted-vmcnt sync: drain batch(kc+1), keep batch(kc+2) in flight ----
        asm volatile("s_waitcnt vmcnt(4)" ::: "memory");
        __builtin_amdgcn_s_barrier();
        __builtin_amdgcn_sched_barrier(0);
        cur = (cur + 1 >= 3) ? 0 : cur + 1;
    }
    #undef STAGE_KV

    // ---- drain all in-flight staging before reusing KV as the Ps buffer ----
    asm volatile("s_waitcnt vmcnt(0)" ::: "memory");
    __builtin_amdgcn_s_barrier();

    // ---- l reduction (lanes sharing l16 across quads) + epilogue ----
    lacc += __shfl_xor(lacc, 16);
    lacc += __shfl_xor(lacc, 32);
    const float inv = 1.0f / lacc;

    short* pw = &KV[0][0][0] + w4 * 1152;   // per-wave 16x72 transpose buffer
    #pragma unroll
    for (int dt = 0; dt < 4; ++dt) {
        *(unsigned*)&pw[l16 * 72 + dt * 16 + quad * 4]     = pk_bf16(ot[dt][0] * inv, ot[dt][1] * inv);
        *(unsigned*)&pw[l16 * 72 + dt * 16 + quad * 4 + 2] = pk_bf16(ot[dt][2] * inv, ot[dt][3] * inv);
    }
    {
        const int qr = lane >> 2, dc = (lane & 3) * 16;
        bf16x8 a0 = *(const bf16x8*)&pw[qr * 72 + dc];
        bf16x8 a1 = *(const bf16x8*)&pw[qr * 72 + dc + 8];
        short* dst = &comb[(rowbase + q0 + qr) * 1024 + hcol + dc];
        *(bf16x8*)dst = a0;
        *(bf16x8*)(dst + 8) = a1;
    }
}

// ---------- launch ----------
extern "C" void kernel_launch(void* const* d_in, const int* in_sizes, int n_in,
                              void* d_out, int out_size, void* d_ws, size_t ws_size,
                              hipStream_t stream)
{
    const float* enc = (const float*)d_in[0];
    const float* Wa  = (const float*)d_in[1];
    const float* ba  = (const float*)d_in[2];
    const float* Wo  = (const float*)d_in[3];
    const float* bo  = (const float*)d_in[4];
    float* out = (float*)d_out;

    // layout (41 MB peak):
    // [0,8)   Abf (dead after gemm1) -> comb
    // [8,10)  WtO    [10,11) biases
    // [11,17) WtA    [17,25) Kx    [25,33) Vx    [33,41) Qw
    char* ws = (char*)d_ws;
    short* Abf  = (short*)ws;
    short* comb = (short*)ws;
    short* WtO  = (short*)(ws + ((size_t)8 << 20));
    short* bbA  = (short*)(ws + ((size_t)10 << 20));
    short* bbO  = (short*)(ws + ((size_t)10 << 20) + 16384);
    short* WtA  = (short*)(ws + ((size_t)11 << 20));
    short* Kx   = (short*)(ws + ((size_t)17 << 20));
    short* Vx   = (short*)(ws + ((size_t)25 << 20));
    short* Qw   = (short*)(ws + ((size_t)33 << 20));

    prep_kernel<<<3074, 256, 0, stream>>>(enc, Wa, ba, Wo, bo, Abf, WtA, bbA, WtO, bbO);
    gemm_bt<128, false, true><<<dim3(24, 32), 256, 0, stream>>>(
        Abf, WtA, bbA, Qw, Kx, Vx, 4096, 3072, 1024);
    attn_kernel<<<1024, 256, 0, stream>>>(Qw, Kx, Vx, comb);
    gemm_bt<64, true, false><<<dim3(16, 32), 256, 0, stream>>>(
        comb, WtO, bbO, out, nullptr, nullptr, 4096, 1024, 1024);
}

// Round 8
// 174.246 us; speedup vs baseline: 1.0903x; 1.0240x over previous
//
#include <hip/hip_runtime.h>
#include <hip/hip_bf16.h>

// ---------- types / helpers ----------
typedef __attribute__((ext_vector_type(8))) short bf16x8;   // 8 bf16 = 4 VGPRs
typedef __attribute__((ext_vector_type(4))) short bf16x4;
typedef __attribute__((ext_vector_type(4))) float f32x4;

__device__ __forceinline__ short f2bf(float f) {
    unsigned u = __float_as_uint(f);
    u += 0x7fff + ((u >> 16) & 1);          // round-to-nearest-even
    return (short)(u >> 16);
}
__device__ __forceinline__ float bf2f(short s) {
    return __uint_as_float(((unsigned)(unsigned short)s) << 16);
}
__device__ __forceinline__ unsigned pk_bf16(float lo, float hi) {
    __hip_bfloat162 t = __float22bfloat162_rn(make_float2(lo, hi));
    unsigned u;
    __builtin_memcpy(&u, &t, 4);
    return u;
}

#define GLOAD_LDS16(gp, lp)                                                            \
    __builtin_amdgcn_global_load_lds(                                                  \
        (const __attribute__((address_space(1))) unsigned*)(gp),                       \
        (__attribute__((address_space(3))) unsigned*)(lp), 16, 0, 0)

#define QK_SCALE 0.180336879f   // (1/sqrt(64)) * log2(e), folded into q at GEMM1
#define MFMA16(a, b, c) __builtin_amdgcn_mfma_f32_16x16x32_bf16((a), (b), (c), 0, 0, 0)

// ---------- fused prep: enc->bf16, biases->bf16, Wa/Wo -> transposed bf16 ----------
__device__ __forceinline__ void tcvt_tile(const float* __restrict__ W, short* __restrict__ Wt,
                                          int K, int N, int bx, int by, int t,
                                          short (*tile)[72]) {
    const int k0 = by * 64, n0 = bx * 64;
    #pragma unroll
    for (int jj = 0; jj < 4; ++jj) {
        int row = jj * 16 + (t >> 4);
        int col = (t & 15) * 4;
        f32x4 v = *(const f32x4*)&W[(size_t)(k0 + row) * N + n0 + col];
        bf16x4 b = {f2bf(v.x), f2bf(v.y), f2bf(v.z), f2bf(v.w)};
        *(bf16x4*)&tile[row][col] = b;
    }
    __syncthreads();
    const int nr = t >> 2, kc = (t & 3) * 16;
    bf16x8 o0, o1;
    #pragma unroll
    for (int j = 0; j < 8; ++j) { o0[j] = tile[kc + j][nr]; o1[j] = tile[kc + 8 + j][nr]; }
    short* dst = &Wt[(size_t)(n0 + nr) * K + k0 + kc];
    *(bf16x8*)dst = o0;
    *(bf16x8*)(dst + 8) = o1;
}

__global__ __launch_bounds__(256) void prep_kernel(
    const float* __restrict__ enc, const float* __restrict__ Wa,
    const float* __restrict__ ba, const float* __restrict__ Wo,
    const float* __restrict__ bo, short* __restrict__ Abf,
    short* __restrict__ WtA, short* __restrict__ bbA,
    short* __restrict__ WtO, short* __restrict__ bbO)
{
    __shared__ alignas(16) short tile[64][72];
    const int id = blockIdx.x, t = threadIdx.x;
    if (id < 2048) {
        const int i = id * 2048 + t * 8;
        f32x4 a = *(const f32x4*)&enc[i];
        f32x4 b = *(const f32x4*)&enc[i + 4];
        bf16x8 o = {f2bf(a.x), f2bf(a.y), f2bf(a.z), f2bf(a.w),
                    f2bf(b.x), f2bf(b.y), f2bf(b.z), f2bf(b.w)};
        *(bf16x8*)&Abf[i] = o;
    } else if (id == 2048) {
        for (int j = t * 8; j < 3072; j += 2048) {
            f32x4 a = *(const f32x4*)&ba[j];
            f32x4 b = *(const f32x4*)&ba[j + 4];
            bf16x8 o = {f2bf(a.x), f2bf(a.y), f2bf(a.z), f2bf(a.w),
                        f2bf(b.x), f2bf(b.y), f2bf(b.z), f2bf(b.w)};
            *(bf16x8*)&bbA[j] = o;
        }
    } else if (id == 2049) {
        if (t < 128) {
            const int j = t * 8;
            f32x4 a = *(const f32x4*)&bo[j];
            f32x4 b = *(const f32x4*)&bo[j + 4];
            bf16x8 o = {f2bf(a.x), f2bf(a.y), f2bf(a.z), f2bf(a.w),
                        f2bf(b.x), f2bf(b.y), f2bf(b.z), f2bf(b.w)};
            *(bf16x8*)&bbO[j] = o;
        }
        __syncthreads();
    } else if (id < 2818) {
        const int lid = id - 2050;
        tcvt_tile(Wa, WtA, 1024, 3072, lid % 48, lid / 48, t, tile);
    } else {
        const int lid = id - 2818;
        tcvt_tile(Wo, WtO, 1024, 1024, lid % 16, lid / 16, t, tile);
    }
}

// ---------- BT GEMM, BK=64, double-buffered 2-phase pipeline ----------
// Round-8: the old K-loop issued staging loads then IMMEDIATELY drained them
// (syncthreads lowers to vmcnt(0)+barrier) -> full L2/L3 latency exposed every
// iteration, MfmaUtil 20%. Now: double-buffered As/Bs; each iteration issues
// STAGE(t+1 -> buf^1) FIRST, computes buf under the in-flight loads, then one
// syncthreads (drain lands after ~500cy of compute: latency hidden; barrier
// count halved). Last iteration clamps to a redundant reload (uniform sched).
// Safety: buffer written at t was read at t-1; all waves passed barrier(t-1)
// whose MFMAs consumed every ds_read before any new write is issued.
// 16B chunks XOR-swizzled by row (chunk ^= row&7) as before. SPLIT3 epilogue
// (fragment-order coalesced Kx/Vx/Q writeout) reuses buffer 0 as the 128x128
// Ct (exactly 32KB). Vx key order PERMUTED so attn's QK accumulator IS the
// PV B-operand: slot (f,quad,j) holds key f*32+(j>>2)*16+quad*4+(j&3).
template<int BN, bool F32OUT, bool SPLIT3>
__global__ __launch_bounds__(256) void gemm_bt(
    const short* __restrict__ A, const short* __restrict__ Bt,
    const short* __restrict__ bias, void* __restrict__ C,
    short* __restrict__ Kw, short* __restrict__ Vw, int M, int N, int K)
{
    __shared__ alignas(16) short LB[2][128 * 64 + BN * 64];
    short* Ct = &LB[0][0];           // SPLIT3 epilogue: [128][128] (exactly 32KB)

    const int tid = threadIdx.x, w = tid >> 6, lane = tid & 63;
    const int quad = lane >> 4, l16 = lane & 15;
    constexpr int MT = (BN == 128) ? 4 : 2;
    const int wm = (BN == 128) ? (w >> 1) : w;
    const int wn = (BN == 128) ? (w & 1) : 0;
    const int m0 = blockIdx.y * 128, n0 = blockIdx.x * BN;
    // staging: one gload16 = 64 lanes x 16B = 8 rows x 128B
    const int srow = lane >> 3;                 // 0..7 within the 8-row chunk
    const int scol = ((lane & 7) ^ srow) * 8;   // pre-swizzled source chunk

    f32x4 acc[MT][4] = {};

    // issue all staging loads for K-tile k0s into LB[buf]
    #define STAGE_G(k0s, buf)                                                               \
        do {                                                                                \
            short* As_ = &LB[buf][0];                                                       \
            short* Bs_ = &LB[buf][128 * 64];                                                \
            _Pragma("unroll")                                                               \
            for (int jj = 0; jj < 4; ++jj) {                                                \
                const int rb = w * 32 + jj * 8;                                             \
                GLOAD_LDS16(&A[(size_t)(m0 + rb + srow) * K + (k0s) + scol], &As_[rb * 64]);\
            }                                                                               \
            if (BN == 128) {                                                                \
                _Pragma("unroll")                                                           \
                for (int jj = 0; jj < 4; ++jj) {                                            \
                    const int rb = w * 32 + jj * 8;                                         \
                    GLOAD_LDS16(&Bt[(size_t)(n0 + rb + srow) * K + (k0s) + scol],           \
                                &Bs_[rb * 64]);                                             \
                }                                                                           \
            } else {                                                                        \
                _Pragma("unroll")                                                           \
                for (int jj = 0; jj < 2; ++jj) {                                            \
                    const int rb = w * 16 + jj * 8;                                         \
                    GLOAD_LDS16(&Bt[(size_t)(n0 + rb + srow) * K + (k0s) + scol],           \
                                &Bs_[rb * 64]);                                             \
                }                                                                           \
            }                                                                               \
        } while (0)

    STAGE_G(0, 0);
    __syncthreads();                 // batch(0) landed; clean start

    int cur = 0;
    for (int k0 = 0; k0 < K; k0 += 64) {
        // ---- issue next tile's loads into the other buffer (overlaps compute) ----
        const int kn = (k0 + 64 < K) ? k0 + 64 : k0;   // clamp: harmless reload on last
        STAGE_G(kn, cur ^ 1);

        // ---- compute current buffer ----
        const short* As = &LB[cur][0];
        const short* Bs = &LB[cur][128 * 64];
        #pragma unroll
        for (int half = 0; half < 2; ++half) {
            const int kc2 = half * 4 + quad;    // 16B chunk index 0..7
            bf16x8 af[MT], bfr[4];
            #pragma unroll
            for (int i = 0; i < MT; ++i) {
                const int row = wm * (MT * 16) + i * 16 + l16;
                af[i] = *(const bf16x8*)&As[row * 64 + ((kc2 ^ (row & 7)) << 3)];
            }
            #pragma unroll
            for (int i = 0; i < 4; ++i) {
                const int row = wn * 64 + i * 16 + l16;
                bfr[i] = *(const bf16x8*)&Bs[row * 64 + ((kc2 ^ (row & 7)) << 3)];
            }
            #pragma unroll
            for (int mt = 0; mt < MT; ++mt)
                #pragma unroll
                for (int nt = 0; nt < 4; ++nt)
                    acc[mt][nt] = MFMA16(af[mt], bfr[nt], acc[mt][nt]);
        }

        // ---- single barrier: drains batch(t+1) AFTER it flew under compute ----
        __syncthreads();
        cur ^= 1;
    }
    #undef STAGE_G

    if (SPLIT3) {
        const int g = n0 >> 10;                     // 0=q,1=k,2=v (block-uniform)
        const int lc0 = n0 & 1023;
        // (last loop barrier already drained everything; LB reusable as Ct)
        // ---- stage 128x128 C tile into LDS, 16B-chunk XOR swizzle ----
        if (g < 2) {
            // row-major: Ct[row][((col>>3) ^ (row&15))*8 + (col&7)]
            #pragma unroll
            for (int nt = 0; nt < 4; ++nt) {
                const int col = wn * 64 + nt * 16 + l16;
                const float bv = bf2f(bias[n0 + col]);
                const int chunk = col >> 3, wi = col & 7;
                #pragma unroll
                for (int mt = 0; mt < 4; ++mt) {
                    const int rbase = wm * 64 + mt * 16 + quad * 4;
                    #pragma unroll
                    for (int r = 0; r < 4; ++r) {
                        const int row = rbase + r;
                        float v = acc[mt][nt][r] + bv;
                        if (g == 0) v *= QK_SCALE;
                        Ct[row * 128 + (((chunk ^ (row & 15)) << 3) | wi)] = f2bf(v);
                    }
                }
            }
        } else {
            // transposed [d][key]: Ct[d][((key>>3) ^ (d&15))*8 + (key&7)],
            // 4 contiguous keys per acc reg quad -> one 8B store
            #pragma unroll
            for (int nt = 0; nt < 4; ++nt) {
                const int d = wn * 64 + nt * 16 + l16;
                const float bv = bf2f(bias[n0 + d]);
                const int dsw = d & 15;
                #pragma unroll
                for (int mt = 0; mt < 4; ++mt) {
                    const int key0 = wm * 64 + mt * 16 + quad * 4;
                    bf16x4 p = {f2bf(acc[mt][nt][0] + bv), f2bf(acc[mt][nt][1] + bv),
                                f2bf(acc[mt][nt][2] + bv), f2bf(acc[mt][nt][3] + bv)};
                    *(bf16x4*)&Ct[d * 128 + ((((key0 >> 3) ^ dsw) << 3) | (key0 & 7))] = p;
                }
            }
        }
        __syncthreads();
        // ---- coalesced writeout ----
        const int batch = m0 >> 11;
        const int kc0 = (m0 & 2047) >> 6;           // even; tile covers kc0, kc0+1
        const int head0 = lc0 >> 6;                 // even; tile covers head0, head0+1
        if (g == 0) {
            short* dst = (short*)C;                 // Qw, row-major [4096][1024]
            #pragma unroll
            for (int i = 0; i < 8; ++i) {
                const int idx = i * 256 + tid;      // 0..2047
                const int row = idx >> 4, chunk = idx & 15;
                bf16x8 v = *(const bf16x8*)&Ct[row * 128 + ((chunk ^ (row & 15)) << 3)];
                *(bf16x8*)&dst[(size_t)(m0 + row) * 1024 + lc0 + chunk * 8] = v;
            }
        } else if (g == 1) {
            // Kx[bh][kc][c=(s*2+h2)*64+lane][j] = K[kc*64+s*16+l16][h2*32+quad*8+j]
            #pragma unroll
            for (int i = 0; i < 8; ++i) {
                const int idx = i * 256 + tid;
                const int qd = idx >> 9, c = idx & 511;
                const int kcL = qd >> 1, headL = qd & 1;
                const int s = c >> 7, h2 = (c >> 6) & 1;
                const int l16c = c & 15, quadc = (c >> 4) & 3;
                const int row = kcL * 64 + s * 16 + l16c;
                const int colc = headL * 8 + h2 * 4 + quadc;
                bf16x8 v = *(const bf16x8*)&Ct[row * 128 + ((colc ^ (row & 15)) << 3)];
                const int bh = batch * 16 + head0 + headL, kc = kc0 + kcL;
                *(bf16x8*)&Kw[((size_t)(bh * 32 + kc) * 512 + c) * 8] = v;
            }
        } else {
            // Vx[bh][kc][c=(h2*4+dt)*64+lane][j] = V[key][dt*16+l16] with the
            // PERMUTED key = kcL*64 + h2*32 + (j>>2)*16 + quadc*4 + (j&3):
            // j=0..3 -> keys Ka..Ka+3, j=4..7 -> keys Ka+16..Ka+19.
            #pragma unroll
            for (int i = 0; i < 8; ++i) {
                const int idx = i * 256 + tid;
                const int qd = idx >> 9, c = idx & 511;
                const int kcL = qd >> 1, headL = qd & 1;
                const int h2 = c >> 8, dt = (c >> 6) & 3;
                const int l16c = c & 15, quadc = (c >> 4) & 3;
                const int d = headL * 64 + dt * 16 + l16c;
                const int Ka = kcL * 64 + h2 * 32 + quadc * 4;
                const int Kb = Ka + 16;
                bf16x4 va = *(const bf16x4*)&Ct[d * 128 + (((Ka >> 3) ^ (d & 15)) << 3) + (Ka & 7)];
                bf16x4 vb = *(const bf16x4*)&Ct[d * 128 + (((Kb >> 3) ^ (d & 15)) << 3) + (Kb & 7)];
                bf16x8 v = {va[0], va[1], va[2], va[3], vb[0], vb[1], vb[2], vb[3]};
                const int bh = batch * 16 + head0 + headL, kc = kc0 + kcL;
                *(bf16x8*)&Vw[((size_t)(bh * 32 + kc) * 512 + c) * 8] = v;
            }
        }
    } else {
        #pragma unroll
        for (int nt = 0; nt < 4; ++nt) {
            const int col = n0 + wn * 64 + nt * 16 + l16;
            const float bv = bf2f(bias[col]);
            #pragma unroll
            for (int mt = 0; mt < MT; ++mt) {
                const int row = m0 + wm * (MT * 16) + mt * 16 + quad * 4;
                #pragma unroll
                for (int r = 0; r < 4; ++r) {
                    float v = acc[mt][nt][r] + bv;
                    if (F32OUT) ((float*)C)[(size_t)(row + r) * N + col] = v;
                    else        ((short*)C)[(size_t)(row + r) * N + col] = f2bf(v);
                }
            }
        }
    }
}

// ---------- causal flash attention: 64-row q-bands, occupancy-first ----------
// One block = one 64-row band (4 waves x 16 rows), keys kc=0..n: every wave
// active every step, uniform trip count. Ps unioned into KV -> 48KB -> 3
// blocks/CU. Grid 1024 blocks, longest-band-first. Counted-vmcnt triple-buffer
// staging pipeline (T3/T4). P never touches LDS: QK accumulator consumed
// directly as PV B-operand via the key-permuted Vx layout.
__global__ __launch_bounds__(256) void attn_kernel(
    const short* __restrict__ Qw, const short* __restrict__ Kx,
    const short* __restrict__ Vx, short* __restrict__ comb)
{
    __shared__ alignas(16) short KV[3][2][4096];      // 48KB; reused as Ps post-loop

    const int tid = threadIdx.x, w4 = tid >> 6, lane = tid & 63;
    const int quad = lane >> 4, l16 = lane & 15;
    const int blk = blockIdx.x;
    const int n = 31 - (blk >> 5);                  // band index, longest first
    const int bh = blk & 31;
    const int batch = bh >> 4, head = bh & 15;
    const size_t rowbase = (size_t)batch * 2048;
    const int hcol = head * 64;
    const int q0 = n * 64 + w4 * 16;                // this wave's 16 q-rows
    const short* Kxbh = Kx + (size_t)bh * 131072;
    const short* Vxbh = Vx + (size_t)bh * 131072;
    const int lofs = lane * 8;

    // Q fragment (B-operand: q = l16, d = quad*8+j (+32))
    bf16x8 qf[2];
    {
        const short* pq = &Qw[(rowbase + q0 + l16) * 1024 + hcol];
        qf[0] = *(const bf16x8*)(pq + quad * 8);
        qf[1] = *(const bf16x8*)(pq + 32 + quad * 8);
    }
    // drain Q loads so in-loop vmcnt counts are statically exact
    asm volatile("s_waitcnt vmcnt(0)" ::: "memory");

    f32x4 ot[4] = {};
    float lacc = 0.f;

    // per-wave staging slice: wave w4 stages chunks {j*256 + w4*64 + lane}
    const int sbase = w4 * 64;

    #define STAGE_KV(kcs, buf)                                                              \
        do {                                                                                \
            const size_t nb_ = (size_t)(kcs)*4096;                                          \
            _Pragma("unroll")                                                               \
            for (int j = 0; j < 2; ++j) {                                                   \
                GLOAD_LDS16(&Kxbh[nb_ + (size_t)(j * 256 + sbase + lane) * 8],              \
                            &KV[buf][0][(j * 256 + sbase) * 8]);                            \
                GLOAD_LDS16(&Vxbh[nb_ + (size_t)(j * 256 + sbase + lane) * 8],              \
                            &KV[buf][1][(j * 256 + sbase) * 8]);                            \
            }                                                                               \
        } while (0)

    // prologue: stage kc=0 -> buf0, kc=min(1,n) -> buf1
    STAGE_KV(0, 0);
    STAGE_KV((n >= 1) ? 1 : 0, 1);
    asm volatile("s_waitcnt vmcnt(4)" ::: "memory");   // drain batch(0), keep batch(1)
    __builtin_amdgcn_s_barrier();
    __builtin_amdgcn_sched_barrier(0);

    int cur = 0;
    for (int kc = 0; kc <= n; ++kc) {
        // ---- issue batch(kc+2) into buf (kc+2)%3 (clamped: uniform 4 loads/step) ----
        {
            const int ks = (kc + 2 <= n) ? kc + 2 : n;
            const int wb = (cur + 2 >= 3) ? cur - 1 : cur + 2;
            STAGE_KV(ks, wb);
        }

        // ---- K fragments from LDS ----
        bf16x8 kf[4][2];
        #pragma unroll
        for (int s = 0; s < 4; ++s) {
            kf[s][0] = *(const bf16x8*)&KV[cur][0][(s * 2 + 0) * 512 + lofs];
            kf[s][1] = *(const bf16x8*)&KV[cur][0][(s * 2 + 1) * 512 + lofs];
        }

        // ---- QK (S^T = K.Q^T) ----
        f32x4 sv[4];
        #pragma unroll
        for (int s = 0; s < 4; ++s) {
            f32x4 a = {0.f, 0.f, 0.f, 0.f};
            a = MFMA16(kf[s][0], qf[0], a);
            a = MFMA16(kf[s][1], qf[1], a);
            sv[s] = a;
        }

        // ---- V fragments from LDS (key-permuted layout) ----
        bf16x8 vf[2][4];
        #pragma unroll
        for (int hh = 0; hh < 2; ++hh)
            #pragma unroll
            for (int dt = 0; dt < 4; ++dt)
                vf[hh][dt] = *(const bf16x8*)&KV[cur][1][(hh * 4 + dt) * 512 + lofs];

        // ---- mask (last step only) -> exp2 -> pack in-register -> PV ----
        if (kc == n) {
            const int qq = q0 + l16;
            #pragma unroll
            for (int s = 0; s < 4; ++s) {
                const int keyb = kc * 64 + s * 16 + quad * 4;
                #pragma unroll
                for (int r = 0; r < 4; ++r)
                    sv[s][r] = (keyb + r <= qq) ? sv[s][r] : -1e30f;
            }
        }
        {
            unsigned u[4][2];
            #pragma unroll
            for (int s = 0; s < 4; ++s) {
                #pragma unroll
                for (int r = 0; r < 4; ++r) sv[s][r] = exp2f(sv[s][r]);
                lacc += (sv[s][0] + sv[s][1]) + (sv[s][2] + sv[s][3]);
                u[s][0] = pk_bf16(sv[s][0], sv[s][1]);
                u[s][1] = pk_bf16(sv[s][2], sv[s][3]);
            }
            bf16x8 pf0, pf1;
            {
                unsigned t0[4] = {u[0][0], u[0][1], u[1][0], u[1][1]};
                unsigned t1[4] = {u[2][0], u[2][1], u[3][0], u[3][1]};
                __builtin_memcpy(&pf0, t0, 16);
                __builtin_memcpy(&pf1, t1, 16);
            }
            #pragma unroll
            for (int dt = 0; dt < 4; ++dt) {
                ot[dt] = MFMA16(vf[0][dt], pf0, ot[dt]);
                ot[dt] = MFMA16(vf[1][dt], pf1, ot[dt]);
            }
        }

        // ---- counted-vmcnt sync: drain batch(kc+1), keep batch(kc+2) in flight ----
        asm volatile("s_waitcnt vmcnt(4)" ::: "memory");
        __builtin_amdgcn_s_barrier();
        __builtin_amdgcn_sched_barrier(0);
        cur = (cur + 1 >= 3) ? 0 : cur + 1;
    }
    #undef STAGE_KV

    // ---- drain all in-flight staging before reusing KV as the Ps buffer ----
    asm volatile("s_waitcnt vmcnt(0)" ::: "memory");
    __builtin_amdgcn_s_barrier();

    // ---- l reduction (lanes sharing l16 across quads) + epilogue ----
    lacc += __shfl_xor(lacc, 16);
    lacc += __shfl_xor(lacc, 32);
    const float inv = 1.0f / lacc;

    short* pw = &KV[0][0][0] + w4 * 1152;   // per-wave 16x72 transpose buffer
    #pragma unroll
    for (int dt = 0; dt < 4; ++dt) {
        *(unsigned*)&pw[l16 * 72 + dt * 16 + quad * 4]     = pk_bf16(ot[dt][0] * inv, ot[dt][1] * inv);
        *(unsigned*)&pw[l16 * 72 + dt * 16 + quad * 4 + 2] = pk_bf16(ot[dt][2] * inv, ot[dt][3] * inv);
    }
    {
        const int qr = lane >> 2, dc = (lane & 3) * 16;
        bf16x8 a0 = *(const bf16x8*)&pw[qr * 72 + dc];
        bf16x8 a1 = *(const bf16x8*)&pw[qr * 72 + dc + 8];
        short* dst = &comb[(rowbase + q0 + qr) * 1024 + hcol + dc];
        *(bf16x8*)dst = a0;
        *(bf16x8*)(dst + 8) = a1;
    }
}

// ---------- launch ----------
extern "C" void kernel_launch(void* const* d_in, const int* in_sizes, int n_in,
                              void* d_out, int out_size, void* d_ws, size_t ws_size,
                              hipStream_t stream)
{
    const float* enc = (const float*)d_in[0];
    const float* Wa  = (const float*)d_in[1];
    const float* ba  = (const float*)d_in[2];
    const float* Wo  = (const float*)d_in[3];
    const float* bo  = (const float*)d_in[4];
    float* out = (float*)d_out;

    // layout (41 MB peak):
    // [0,8)   Abf (dead after gemm1) -> comb
    // [8,10)  WtO    [10,11) biases
    // [11,17) WtA    [17,25) Kx    [25,33) Vx    [33,41) Qw
    char* ws = (char*)d_ws;
    short* Abf  = (short*)ws;
    short* comb = (short*)ws;
    short* WtO  = (short*)(ws + ((size_t)8 << 20));
    short* bbA  = (short*)(ws + ((size_t)10 << 20));
    short* bbO  = (short*)(ws + ((size_t)10 << 20) + 16384);
    short* WtA  = (short*)(ws + ((size_t)11 << 20));
    short* Kx   = (short*)(ws + ((size_t)17 << 20));
    short* Vx   = (short*)(ws + ((size_t)25 << 20));
    short* Qw   = (short*)(ws + ((size_t)33 << 20));

    prep_kernel<<<3074, 256, 0, stream>>>(enc, Wa, ba, Wo, bo, Abf, WtA, bbA, WtO, bbO);
    gemm_bt<128, false, true><<<dim3(24, 32), 256, 0, stream>>>(
        Abf, WtA, bbA, Qw, Kx, Vx, 4096, 3072, 1024);
    attn_kernel<<<1024, 256, 0, stream>>>(Qw, Kx, Vx, comb);
    gemm_bt<64, true, false><<<dim3(16, 32), 256, 0, stream>>>(
        comb, WtO, bbO, out, nullptr, nullptr, 4096, 1024, 1024);
}

// Round 9
// 171.025 us; speedup vs baseline: 1.1108x; 1.0188x over previous
//
#include <hip/hip_runtime.h>
#include <hip/hip_bf16.h>

// ---------- types / helpers ----------
typedef __attribute__((ext_vector_type(8))) short bf16x8;   // 8 bf16 = 4 VGPRs
typedef __attribute__((ext_vector_type(4))) short bf16x4;
typedef __attribute__((ext_vector_type(4))) float f32x4;

__device__ __forceinline__ short f2bf(float f) {
    unsigned u = __float_as_uint(f);
    u += 0x7fff + ((u >> 16) & 1);          // round-to-nearest-even
    return (short)(u >> 16);
}
__device__ __forceinline__ float bf2f(short s) {
    return __uint_as_float(((unsigned)(unsigned short)s) << 16);
}
__device__ __forceinline__ unsigned pk_bf16(float lo, float hi) {
    __hip_bfloat162 t = __float22bfloat162_rn(make_float2(lo, hi));
    unsigned u;
    __builtin_memcpy(&u, &t, 4);
    return u;
}

#define GLOAD_LDS16(gp, lp)                                                            \
    __builtin_amdgcn_global_load_lds(                                                  \
        (const __attribute__((address_space(1))) unsigned*)(gp),                       \
        (__attribute__((address_space(3))) unsigned*)(lp), 16, 0, 0)

#define QK_SCALE 0.180336879f   // (1/sqrt(64)) * log2(e), folded into q at GEMM1
#define MFMA16(a, b, c) __builtin_amdgcn_mfma_f32_16x16x32_bf16((a), (b), (c), 0, 0, 0)

// ---------- fused prep: enc->bf16, biases->bf16, Wa/Wo -> transposed bf16 ----------
__device__ __forceinline__ void tcvt_tile(const float* __restrict__ W, short* __restrict__ Wt,
                                          int K, int N, int bx, int by, int t,
                                          short (*tile)[72]) {
    const int k0 = by * 64, n0 = bx * 64;
    #pragma unroll
    for (int jj = 0; jj < 4; ++jj) {
        int row = jj * 16 + (t >> 4);
        int col = (t & 15) * 4;
        f32x4 v = *(const f32x4*)&W[(size_t)(k0 + row) * N + n0 + col];
        bf16x4 b = {f2bf(v.x), f2bf(v.y), f2bf(v.z), f2bf(v.w)};
        *(bf16x4*)&tile[row][col] = b;
    }
    __syncthreads();
    const int nr = t >> 2, kc = (t & 3) * 16;
    bf16x8 o0, o1;
    #pragma unroll
    for (int j = 0; j < 8; ++j) { o0[j] = tile[kc + j][nr]; o1[j] = tile[kc + 8 + j][nr]; }
    short* dst = &Wt[(size_t)(n0 + nr) * K + k0 + kc];
    *(bf16x8*)dst = o0;
    *(bf16x8*)(dst + 8) = o1;
}

__global__ __launch_bounds__(256) void prep_kernel(
    const float* __restrict__ enc, const float* __restrict__ Wa,
    const float* __restrict__ ba, const float* __restrict__ Wo,
    const float* __restrict__ bo, short* __restrict__ Abf,
    short* __restrict__ WtA, short* __restrict__ bbA,
    short* __restrict__ WtO, short* __restrict__ bbO)
{
    __shared__ alignas(16) short tile[64][72];
    const int id = blockIdx.x, t = threadIdx.x;
    if (id < 2048) {
        const int i = id * 2048 + t * 8;
        f32x4 a = *(const f32x4*)&enc[i];
        f32x4 b = *(const f32x4*)&enc[i + 4];
        bf16x8 o = {f2bf(a.x), f2bf(a.y), f2bf(a.z), f2bf(a.w),
                    f2bf(b.x), f2bf(b.y), f2bf(b.z), f2bf(b.w)};
        *(bf16x8*)&Abf[i] = o;
    } else if (id == 2048) {
        for (int j = t * 8; j < 3072; j += 2048) {
            f32x4 a = *(const f32x4*)&ba[j];
            f32x4 b = *(const f32x4*)&ba[j + 4];
            bf16x8 o = {f2bf(a.x), f2bf(a.y), f2bf(a.z), f2bf(a.w),
                        f2bf(b.x), f2bf(b.y), f2bf(b.z), f2bf(b.w)};
            *(bf16x8*)&bbA[j] = o;
        }
    } else if (id == 2049) {
        if (t < 128) {
            const int j = t * 8;
            f32x4 a = *(const f32x4*)&bo[j];
            f32x4 b = *(const f32x4*)&bo[j + 4];
            bf16x8 o = {f2bf(a.x), f2bf(a.y), f2bf(a.z), f2bf(a.w),
                        f2bf(b.x), f2bf(b.y), f2bf(b.z), f2bf(b.w)};
            *(bf16x8*)&bbO[j] = o;
        }
        __syncthreads();
    } else if (id < 2818) {
        const int lid = id - 2050;
        tcvt_tile(Wa, WtA, 1024, 3072, lid % 48, lid / 48, t, tile);
    } else {
        const int lid = id - 2818;
        tcvt_tile(Wo, WtO, 1024, 1024, lid % 16, lid / 16, t, tile);
    }
}

// ---------- BT GEMM, BK=64, double-buffered counted-vmcnt pipeline ----------
// Round-9: round-8's __syncthreads at step end drained the JUST-ISSUED batch
// (vmcnt(0)) -> ~300-500cy of exposed load latency per iteration. Now the
// drain is counted (T4): at step top, after issuing batch(t+1), wait
// vmcnt(NLD) -- drains batch(t), which had a full step to land; batch(t+1)
// stays in flight across both barriers. Two raw s_barriers/step:
//   entry (after vmcnt): batch(t) collectively visible before ds_reads;
//   exit  (after MFMAs): reads of buf[cur] done before t+1 writes to it
//     (ds_read results are register-consumed by the MFMAs pre-barrier).
// Post-loop vmcnt(0)+barrier: the clamped redundant last batch is still in
// flight and targets buf0 == Ct -- must land before the epilogue reuses it.
// 16B chunks XOR-swizzled by row (chunk ^= row&7). SPLIT3 epilogue writes
// Q/Kx/Vx in attn fragment order; Vx key order PERMUTED so attn's QK
// accumulator IS the PV B-operand: slot (f,quad,j) holds key
// f*32+(j>>2)*16+quad*4+(j&3).
template<int BN, bool F32OUT, bool SPLIT3>
__global__ __launch_bounds__(256) void gemm_bt(
    const short* __restrict__ A, const short* __restrict__ Bt,
    const short* __restrict__ bias, void* __restrict__ C,
    short* __restrict__ Kw, short* __restrict__ Vw, int M, int N, int K)
{
    __shared__ alignas(16) short LB[2][128 * 64 + BN * 64];
    short* Ct = &LB[0][0];           // SPLIT3 epilogue: [128][128] (exactly 32KB)

    const int tid = threadIdx.x, w = tid >> 6, lane = tid & 63;
    const int quad = lane >> 4, l16 = lane & 15;
    constexpr int MT = (BN == 128) ? 4 : 2;
    const int wm = (BN == 128) ? (w >> 1) : w;
    const int wn = (BN == 128) ? (w & 1) : 0;
    const int m0 = blockIdx.y * 128, n0 = blockIdx.x * BN;
    // staging: one gload16 = 64 lanes x 16B = 8 rows x 128B
    const int srow = lane >> 3;                 // 0..7 within the 8-row chunk
    const int scol = ((lane & 7) ^ srow) * 8;   // pre-swizzled source chunk

    f32x4 acc[MT][4] = {};

    // issue all staging loads for K-tile k0s into LB[buf]
    #define STAGE_G(k0s, buf)                                                               \
        do {                                                                                \
            short* As_ = &LB[buf][0];                                                       \
            short* Bs_ = &LB[buf][128 * 64];                                                \
            _Pragma("unroll")                                                               \
            for (int jj = 0; jj < 4; ++jj) {                                                \
                const int rb = w * 32 + jj * 8;                                             \
                GLOAD_LDS16(&A[(size_t)(m0 + rb + srow) * K + (k0s) + scol], &As_[rb * 64]);\
            }                                                                               \
            if (BN == 128) {                                                                \
                _Pragma("unroll")                                                           \
                for (int jj = 0; jj < 4; ++jj) {                                            \
                    const int rb = w * 32 + jj * 8;                                         \
                    GLOAD_LDS16(&Bt[(size_t)(n0 + rb + srow) * K + (k0s) + scol],           \
                                &Bs_[rb * 64]);                                             \
                }                                                                           \
            } else {                                                                        \
                _Pragma("unroll")                                                           \
                for (int jj = 0; jj < 2; ++jj) {                                            \
                    const int rb = w * 16 + jj * 8;                                         \
                    GLOAD_LDS16(&Bt[(size_t)(n0 + rb + srow) * K + (k0s) + scol],           \
                                &Bs_[rb * 64]);                                             \
                }                                                                           \
            }                                                                               \
        } while (0)

    STAGE_G(0, 0);

    int cur = 0;
    for (int k0 = 0; k0 < K; k0 += 64) {
        // ---- issue next tile's loads into the other buffer ----
        const int kn = (k0 + 64 < K) ? k0 + 64 : k0;   // clamp: uniform issue count
        STAGE_G(kn, cur ^ 1);

        // ---- counted drain: batch(t) landed, batch(t+1) stays in flight ----
        if (BN == 128) asm volatile("s_waitcnt vmcnt(8)" ::: "memory");
        else           asm volatile("s_waitcnt vmcnt(6)" ::: "memory");
        __builtin_amdgcn_s_barrier();
        __builtin_amdgcn_sched_barrier(0);

        // ---- compute current buffer ----
        const short* As = &LB[cur][0];
        const short* Bs = &LB[cur][128 * 64];
        #pragma unroll
        for (int half = 0; half < 2; ++half) {
            const int kc2 = half * 4 + quad;    // 16B chunk index 0..7
            bf16x8 af[MT], bfr[4];
            #pragma unroll
            for (int i = 0; i < MT; ++i) {
                const int row = wm * (MT * 16) + i * 16 + l16;
                af[i] = *(const bf16x8*)&As[row * 64 + ((kc2 ^ (row & 7)) << 3)];
            }
            #pragma unroll
            for (int i = 0; i < 4; ++i) {
                const int row = wn * 64 + i * 16 + l16;
                bfr[i] = *(const bf16x8*)&Bs[row * 64 + ((kc2 ^ (row & 7)) << 3)];
            }
            #pragma unroll
            for (int mt = 0; mt < MT; ++mt)
                #pragma unroll
                for (int nt = 0; nt < 4; ++nt)
                    acc[mt][nt] = MFMA16(af[mt], bfr[nt], acc[mt][nt]);
        }

        // ---- exit barrier: reads of buf[cur] complete before t+1 writes it ----
        __builtin_amdgcn_s_barrier();
        cur ^= 1;
    }
    #undef STAGE_G

    // drain the redundant in-flight batch (targets buf0 == Ct) before reuse
    asm volatile("s_waitcnt vmcnt(0)" ::: "memory");
    __builtin_amdgcn_s_barrier();

    if (SPLIT3) {
        const int g = n0 >> 10;                     // 0=q,1=k,2=v (block-uniform)
        const int lc0 = n0 & 1023;
        // ---- stage 128x128 C tile into LDS, 16B-chunk XOR swizzle ----
        if (g < 2) {
            // row-major: Ct[row][((col>>3) ^ (row&15))*8 + (col&7)]
            #pragma unroll
            for (int nt = 0; nt < 4; ++nt) {
                const int col = wn * 64 + nt * 16 + l16;
                const float bv = bf2f(bias[n0 + col]);
                const int chunk = col >> 3, wi = col & 7;
                #pragma unroll
                for (int mt = 0; mt < 4; ++mt) {
                    const int rbase = wm * 64 + mt * 16 + quad * 4;
                    #pragma unroll
                    for (int r = 0; r < 4; ++r) {
                        const int row = rbase + r;
                        float v = acc[mt][nt][r] + bv;
                        if (g == 0) v *= QK_SCALE;
                        Ct[row * 128 + (((chunk ^ (row & 15)) << 3) | wi)] = f2bf(v);
                    }
                }
            }
        } else {
            // transposed [d][key]: Ct[d][((key>>3) ^ (d&15))*8 + (key&7)],
            // 4 contiguous keys per acc reg quad -> one 8B store
            #pragma unroll
            for (int nt = 0; nt < 4; ++nt) {
                const int d = wn * 64 + nt * 16 + l16;
                const float bv = bf2f(bias[n0 + d]);
                const int dsw = d & 15;
                #pragma unroll
                for (int mt = 0; mt < 4; ++mt) {
                    const int key0 = wm * 64 + mt * 16 + quad * 4;
                    bf16x4 p = {f2bf(acc[mt][nt][0] + bv), f2bf(acc[mt][nt][1] + bv),
                                f2bf(acc[mt][nt][2] + bv), f2bf(acc[mt][nt][3] + bv)};
                    *(bf16x4*)&Ct[d * 128 + ((((key0 >> 3) ^ dsw) << 3) | (key0 & 7))] = p;
                }
            }
        }
        __syncthreads();
        // ---- coalesced writeout ----
        const int batch = m0 >> 11;
        const int kc0 = (m0 & 2047) >> 6;           // even; tile covers kc0, kc0+1
        const int head0 = lc0 >> 6;                 // even; tile covers head0, head0+1
        if (g == 0) {
            short* dst = (short*)C;                 // Qw, row-major [4096][1024]
            #pragma unroll
            for (int i = 0; i < 8; ++i) {
                const int idx = i * 256 + tid;      // 0..2047
                const int row = idx >> 4, chunk = idx & 15;
                bf16x8 v = *(const bf16x8*)&Ct[row * 128 + ((chunk ^ (row & 15)) << 3)];
                *(bf16x8*)&dst[(size_t)(m0 + row) * 1024 + lc0 + chunk * 8] = v;
            }
        } else if (g == 1) {
            // Kx[bh][kc][c=(s*2+h2)*64+lane][j] = K[kc*64+s*16+l16][h2*32+quad*8+j]
            #pragma unroll
            for (int i = 0; i < 8; ++i) {
                const int idx = i * 256 + tid;
                const int qd = idx >> 9, c = idx & 511;
                const int kcL = qd >> 1, headL = qd & 1;
                const int s = c >> 7, h2 = (c >> 6) & 1;
                const int l16c = c & 15, quadc = (c >> 4) & 3;
                const int row = kcL * 64 + s * 16 + l16c;
                const int colc = headL * 8 + h2 * 4 + quadc;
                bf16x8 v = *(const bf16x8*)&Ct[row * 128 + ((colc ^ (row & 15)) << 3)];
                const int bh = batch * 16 + head0 + headL, kc = kc0 + kcL;
                *(bf16x8*)&Kw[((size_t)(bh * 32 + kc) * 512 + c) * 8] = v;
            }
        } else {
            // Vx[bh][kc][c=(h2*4+dt)*64+lane][j] = V[key][dt*16+l16] with the
            // PERMUTED key = kcL*64 + h2*32 + (j>>2)*16 + quadc*4 + (j&3):
            // j=0..3 -> keys Ka..Ka+3, j=4..7 -> keys Ka+16..Ka+19.
            #pragma unroll
            for (int i = 0; i < 8; ++i) {
                const int idx = i * 256 + tid;
                const int qd = idx >> 9, c = idx & 511;
                const int kcL = qd >> 1, headL = qd & 1;
                const int h2 = c >> 8, dt = (c >> 6) & 3;
                const int l16c = c & 15, quadc = (c >> 4) & 3;
                const int d = headL * 64 + dt * 16 + l16c;
                const int Ka = kcL * 64 + h2 * 32 + quadc * 4;
                const int Kb = Ka + 16;
                bf16x4 va = *(const bf16x4*)&Ct[d * 128 + (((Ka >> 3) ^ (d & 15)) << 3) + (Ka & 7)];
                bf16x4 vb = *(const bf16x4*)&Ct[d * 128 + (((Kb >> 3) ^ (d & 15)) << 3) + (Kb & 7)];
                bf16x8 v = {va[0], va[1], va[2], va[3], vb[0], vb[1], vb[2], vb[3]};
                const int bh = batch * 16 + head0 + headL, kc = kc0 + kcL;
                *(bf16x8*)&Vw[((size_t)(bh * 32 + kc) * 512 + c) * 8] = v;
            }
        }
    } else {
        #pragma unroll
        for (int nt = 0; nt < 4; ++nt) {
            const int col = n0 + wn * 64 + nt * 16 + l16;
            const float bv = bf2f(bias[col]);
            #pragma unroll
            for (int mt = 0; mt < MT; ++mt) {
                const int row = m0 + wm * (MT * 16) + mt * 16 + quad * 4;
                #pragma unroll
                for (int r = 0; r < 4; ++r) {
                    float v = acc[mt][nt][r] + bv;
                    if (F32OUT) ((float*)C)[(size_t)(row + r) * N + col] = v;
                    else        ((short*)C)[(size_t)(row + r) * N + col] = f2bf(v);
                }
            }
        }
    }
}

// ---------- causal flash attention: 64-row q-bands, occupancy-first ----------
// One block = one 64-row band (4 waves x 16 rows), keys kc=0..n: every wave
// active every step, uniform trip count. Ps unioned into KV -> 48KB -> 3
// blocks/CU. Grid 1024 blocks, longest-band-first. Counted-vmcnt triple-buffer
// staging pipeline (T3/T4). P never touches LDS: QK accumulator consumed
// directly as PV B-operand via the key-permuted Vx layout.
__global__ __launch_bounds__(256) void attn_kernel(
    const short* __restrict__ Qw, const short* __restrict__ Kx,
    const short* __restrict__ Vx, short* __restrict__ comb)
{
    __shared__ alignas(16) short KV[3][2][4096];      // 48KB; reused as Ps post-loop

    const int tid = threadIdx.x, w4 = tid >> 6, lane = tid & 63;
    const int quad = lane >> 4, l16 = lane & 15;
    const int blk = blockIdx.x;
    const int n = 31 - (blk >> 5);                  // band index, longest first
    const int bh = blk & 31;
    const int batch = bh >> 4, head = bh & 15;
    const size_t rowbase = (size_t)batch * 2048;
    const int hcol = head * 64;
    const int q0 = n * 64 + w4 * 16;                // this wave's 16 q-rows
    const short* Kxbh = Kx + (size_t)bh * 131072;
    const short* Vxbh = Vx + (size_t)bh * 131072;
    const int lofs = lane * 8;

    // Q fragment (B-operand: q = l16, d = quad*8+j (+32))
    bf16x8 qf[2];
    {
        const short* pq = &Qw[(rowbase + q0 + l16) * 1024 + hcol];
        qf[0] = *(const bf16x8*)(pq + quad * 8);
        qf[1] = *(const bf16x8*)(pq + 32 + quad * 8);
    }
    // drain Q loads so in-loop vmcnt counts are statically exact
    asm volatile("s_waitcnt vmcnt(0)" ::: "memory");

    f32x4 ot[4] = {};
    float lacc = 0.f;

    // per-wave staging slice: wave w4 stages chunks {j*256 + w4*64 + lane}
    const int sbase = w4 * 64;

    #define STAGE_KV(kcs, buf)                                                              \
        do {                                                                                \
            const size_t nb_ = (size_t)(kcs)*4096;                                          \
            _Pragma("unroll")                                                               \
            for (int j = 0; j < 2; ++j) {                                                   \
                GLOAD_LDS16(&Kxbh[nb_ + (size_t)(j * 256 + sbase + lane) * 8],              \
                            &KV[buf][0][(j * 256 + sbase) * 8]);                            \
                GLOAD_LDS16(&Vxbh[nb_ + (size_t)(j * 256 + sbase + lane) * 8],              \
                            &KV[buf][1][(j * 256 + sbase) * 8]);                            \
            }                                                                               \
        } while (0)

    // prologue: stage kc=0 -> buf0, kc=min(1,n) -> buf1
    STAGE_KV(0, 0);
    STAGE_KV((n >= 1) ? 1 : 0, 1);
    asm volatile("s_waitcnt vmcnt(4)" ::: "memory");   // drain batch(0), keep batch(1)
    __builtin_amdgcn_s_barrier();
    __builtin_amdgcn_sched_barrier(0);

    int cur = 0;
    for (int kc = 0; kc <= n; ++kc) {
        // ---- issue batch(kc+2) into buf (kc+2)%3 (clamped: uniform 4 loads/step) ----
        {
            const int ks = (kc + 2 <= n) ? kc + 2 : n;
            const int wb = (cur + 2 >= 3) ? cur - 1 : cur + 2;
            STAGE_KV(ks, wb);
        }

        // ---- K fragments from LDS ----
        bf16x8 kf[4][2];
        #pragma unroll
        for (int s = 0; s < 4; ++s) {
            kf[s][0] = *(const bf16x8*)&KV[cur][0][(s * 2 + 0) * 512 + lofs];
            kf[s][1] = *(const bf16x8*)&KV[cur][0][(s * 2 + 1) * 512 + lofs];
        }

        // ---- QK (S^T = K.Q^T) ----
        f32x4 sv[4];
        #pragma unroll
        for (int s = 0; s < 4; ++s) {
            f32x4 a = {0.f, 0.f, 0.f, 0.f};
            a = MFMA16(kf[s][0], qf[0], a);
            a = MFMA16(kf[s][1], qf[1], a);
            sv[s] = a;
        }

        // ---- V fragments from LDS (key-permuted layout) ----
        bf16x8 vf[2][4];
        #pragma unroll
        for (int hh = 0; hh < 2; ++hh)
            #pragma unroll
            for (int dt = 0; dt < 4; ++dt)
                vf[hh][dt] = *(const bf16x8*)&KV[cur][1][(hh * 4 + dt) * 512 + lofs];

        // ---- mask (last step only) -> exp2 -> pack in-register -> PV ----
        if (kc == n) {
            const int qq = q0 + l16;
            #pragma unroll
            for (int s = 0; s < 4; ++s) {
                const int keyb = kc * 64 + s * 16 + quad * 4;
                #pragma unroll
                for (int r = 0; r < 4; ++r)
                    sv[s][r] = (keyb + r <= qq) ? sv[s][r] : -1e30f;
            }
        }
        {
            unsigned u[4][2];
            #pragma unroll
            for (int s = 0; s < 4; ++s) {
                #pragma unroll
                for (int r = 0; r < 4; ++r) sv[s][r] = exp2f(sv[s][r]);
                lacc += (sv[s][0] + sv[s][1]) + (sv[s][2] + sv[s][3]);
                u[s][0] = pk_bf16(sv[s][0], sv[s][1]);
                u[s][1] = pk_bf16(sv[s][2], sv[s][3]);
            }
            bf16x8 pf0, pf1;
            {
                unsigned t0[4] = {u[0][0], u[0][1], u[1][0], u[1][1]};
                unsigned t1[4] = {u[2][0], u[2][1], u[3][0], u[3][1]};
                __builtin_memcpy(&pf0, t0, 16);
                __builtin_memcpy(&pf1, t1, 16);
            }
            #pragma unroll
            for (int dt = 0; dt < 4; ++dt) {
                ot[dt] = MFMA16(vf[0][dt], pf0, ot[dt]);
                ot[dt] = MFMA16(vf[1][dt], pf1, ot[dt]);
            }
        }

        // ---- counted-vmcnt sync: drain batch(kc+1), keep batch(kc+2) in flight ----
        asm volatile("s_waitcnt vmcnt(4)" ::: "memory");
        __builtin_amdgcn_s_barrier();
        __builtin_amdgcn_sched_barrier(0);
        cur = (cur + 1 >= 3) ? 0 : cur + 1;
    }
    #undef STAGE_KV

    // ---- drain all in-flight staging before reusing KV as the Ps buffer ----
    asm volatile("s_waitcnt vmcnt(0)" ::: "memory");
    __builtin_amdgcn_s_barrier();

    // ---- l reduction (lanes sharing l16 across quads) + epilogue ----
    lacc += __shfl_xor(lacc, 16);
    lacc += __shfl_xor(lacc, 32);
    const float inv = 1.0f / lacc;

    short* pw = &KV[0][0][0] + w4 * 1152;   // per-wave 16x72 transpose buffer
    #pragma unroll
    for (int dt = 0; dt < 4; ++dt) {
        *(unsigned*)&pw[l16 * 72 + dt * 16 + quad * 4]     = pk_bf16(ot[dt][0] * inv, ot[dt][1] * inv);
        *(unsigned*)&pw[l16 * 72 + dt * 16 + quad * 4 + 2] = pk_bf16(ot[dt][2] * inv, ot[dt][3] * inv);
    }
    {
        const int qr = lane >> 2, dc = (lane & 3) * 16;
        bf16x8 a0 = *(const bf16x8*)&pw[qr * 72 + dc];
        bf16x8 a1 = *(const bf16x8*)&pw[qr * 72 + dc + 8];
        short* dst = &comb[(rowbase + q0 + qr) * 1024 + hcol + dc];
        *(bf16x8*)dst = a0;
        *(bf16x8*)(dst + 8) = a1;
    }
}

// ---------- launch ----------
extern "C" void kernel_launch(void* const* d_in, const int* in_sizes, int n_in,
                              void* d_out, int out_size, void* d_ws, size_t ws_size,
                              hipStream_t stream)
{
    const float* enc = (const float*)d_in[0];
    const float* Wa  = (const float*)d_in[1];
    const float* ba  = (const float*)d_in[2];
    const float* Wo  = (const float*)d_in[3];
    const float* bo  = (const float*)d_in[4];
    float* out = (float*)d_out;

    // layout (41 MB peak):
    // [0,8)   Abf (dead after gemm1) -> comb
    // [8,10)  WtO    [10,11) biases
    // [11,17) WtA    [17,25) Kx    [25,33) Vx    [33,41) Qw
    char* ws = (char*)d_ws;
    short* Abf  = (short*)ws;
    short* comb = (short*)ws;
    short* WtO  = (short*)(ws + ((size_t)8 << 20));
    short* bbA  = (short*)(ws + ((size_t)10 << 20));
    short* bbO  = (short*)(ws + ((size_t)10 << 20) + 16384);
    short* WtA  = (short*)(ws + ((size_t)11 << 20));
    short* Kx   = (short*)(ws + ((size_t)17 << 20));
    short* Vx   = (short*)(ws + ((size_t)25 << 20));
    short* Qw   = (short*)(ws + ((size_t)33 << 20));

    prep_kernel<<<3074, 256, 0, stream>>>(enc, Wa, ba, Wo, bo, Abf, WtA, bbA, WtO, bbO);
    gemm_bt<128, false, true><<<dim3(24, 32), 256, 0, stream>>>(
        Abf, WtA, bbA, Qw, Kx, Vx, 4096, 3072, 1024);
    attn_kernel<<<1024, 256, 0, stream>>>(Qw, Kx, Vx, comb);
    gemm_bt<64, true, false><<<dim3(16, 32), 256, 0, stream>>>(
        comb, WtO, bbO, out, nullptr, nullptr, 4096, 1024, 1024);
}

// Round 11
// 169.625 us; speedup vs baseline: 1.1200x; 1.0083x over previous
//
#include <hip/hip_runtime.h>
#include <hip/hip_bf16.h>

// ---------- types / helpers ----------
typedef __attribute__((ext_vector_type(8))) short bf16x8;   // 8 bf16 = 4 VGPRs
typedef __attribute__((ext_vector_type(4))) short bf16x4;
typedef __attribute__((ext_vector_type(4))) float f32x4;

__device__ __forceinline__ short f2bf(float f) {
    unsigned u = __float_as_uint(f);
    u += 0x7fff + ((u >> 16) & 1);          // round-to-nearest-even
    return (short)(u >> 16);
}
__device__ __forceinline__ float bf2f(short s) {
    return __uint_as_float(((unsigned)(unsigned short)s) << 16);
}
__device__ __forceinline__ unsigned pk_bf16(float lo, float hi) {
    __hip_bfloat162 t = __float22bfloat162_rn(make_float2(lo, hi));
    unsigned u;
    __builtin_memcpy(&u, &t, 4);
    return u;
}

#define GLOAD_LDS16(gp, lp)                                                            \
    __builtin_amdgcn_global_load_lds(                                                  \
        (const __attribute__((address_space(1))) unsigned*)(gp),                       \
        (__attribute__((address_space(3))) unsigned*)(lp), 16, 0, 0)

#define QK_SCALE 0.180336879f   // (1/sqrt(64)) * log2(e), folded into q at GEMM1
#define MFMA16(a, b, c) __builtin_amdgcn_mfma_f32_16x16x32_bf16((a), (b), (c), 0, 0, 0)

// ---------- fused prep: enc->bf16, biases->bf16, Wa/Wo -> transposed bf16 ----------
__device__ __forceinline__ void tcvt_tile(const float* __restrict__ W, short* __restrict__ Wt,
                                          int K, int N, int bx, int by, int t,
                                          short (*tile)[72]) {
    const int k0 = by * 64, n0 = bx * 64;
    #pragma unroll
    for (int jj = 0; jj < 4; ++jj) {
        int row = jj * 16 + (t >> 4);
        int col = (t & 15) * 4;
        f32x4 v = *(const f32x4*)&W[(size_t)(k0 + row) * N + n0 + col];
        bf16x4 b = {f2bf(v.x), f2bf(v.y), f2bf(v.z), f2bf(v.w)};
        *(bf16x4*)&tile[row][col] = b;
    }
    __syncthreads();
    const int nr = t >> 2, kc = (t & 3) * 16;
    bf16x8 o0, o1;
    #pragma unroll
    for (int j = 0; j < 8; ++j) { o0[j] = tile[kc + j][nr]; o1[j] = tile[kc + 8 + j][nr]; }
    short* dst = &Wt[(size_t)(n0 + nr) * K + k0 + kc];
    *(bf16x8*)dst = o0;
    *(bf16x8*)(dst + 8) = o1;
}

__global__ __launch_bounds__(256) void prep_kernel(
    const float* __restrict__ enc, const float* __restrict__ Wa,
    const float* __restrict__ ba, const float* __restrict__ Wo,
    const float* __restrict__ bo, short* __restrict__ Abf,
    short* __restrict__ WtA, short* __restrict__ bbA,
    short* __restrict__ WtO, short* __restrict__ bbO)
{
    __shared__ alignas(16) short tile[64][72];
    const int id = blockIdx.x, t = threadIdx.x;
    if (id < 2048) {
        const int i = id * 2048 + t * 8;
        f32x4 a = *(const f32x4*)&enc[i];
        f32x4 b = *(const f32x4*)&enc[i + 4];
        bf16x8 o = {f2bf(a.x), f2bf(a.y), f2bf(a.z), f2bf(a.w),
                    f2bf(b.x), f2bf(b.y), f2bf(b.z), f2bf(b.w)};
        *(bf16x8*)&Abf[i] = o;
    } else if (id == 2048) {
        for (int j = t * 8; j < 3072; j += 2048) {
            f32x4 a = *(const f32x4*)&ba[j];
            f32x4 b = *(const f32x4*)&ba[j + 4];
            bf16x8 o = {f2bf(a.x), f2bf(a.y), f2bf(a.z), f2bf(a.w),
                        f2bf(b.x), f2bf(b.y), f2bf(b.z), f2bf(b.w)};
            *(bf16x8*)&bbA[j] = o;
        }
    } else if (id == 2049) {
        if (t < 128) {
            const int j = t * 8;
            f32x4 a = *(const f32x4*)&bo[j];
            f32x4 b = *(const f32x4*)&bo[j + 4];
            bf16x8 o = {f2bf(a.x), f2bf(a.y), f2bf(a.z), f2bf(a.w),
                        f2bf(b.x), f2bf(b.y), f2bf(b.z), f2bf(b.w)};
            *(bf16x8*)&bbO[j] = o;
        }
        __syncthreads();
    } else if (id < 2818) {
        const int lid = id - 2050;
        tcvt_tile(Wa, WtA, 1024, 3072, lid % 48, lid / 48, t, tile);
    } else {
        const int lid = id - 2818;
        tcvt_tile(Wo, WtO, 1024, 1024, lid % 16, lid / 16, t, tile);
    }
}

// ---------- BT GEMM, BK=64, double-buffered counted-vmcnt pipeline ----------
// Counted drain (T4): at step top, after issuing batch(t+1), wait vmcnt(NLD)
// -- drains batch(t) (full step to land), batch(t+1) stays in flight across
// both barriers. Entry barrier after vmcnt: batch(t) collectively visible;
// exit barrier after MFMAs: reads of buf[cur] done before t+1 writes it.
// Post-loop vmcnt(0)+barrier before reusing buf0 as Ct.
// gemm2 runs BN=128 (launch change): MFMA:LDS-port ratio 16:12 -> 32:16 per
// wave-step (the BN=64 shape was LDS-port-bound); T5 s_setprio(1) wraps the
// MFMA clusters (scheduler prefers MFMA waves).
// 16B chunks XOR-swizzled by row (chunk ^= row&7). SPLIT3 epilogue writes
// Q/Kx/Vx in attn fragment order; Vx key order PERMUTED so attn's QK
// accumulator IS the PV B-operand: slot (f,quad,j) holds key
// f*32+(j>>2)*16+quad*4+(j&3).
template<int BN, bool F32OUT, bool SPLIT3>
__global__ __launch_bounds__(256) void gemm_bt(
    const short* __restrict__ A, const short* __restrict__ Bt,
    const short* __restrict__ bias, void* __restrict__ C,
    short* __restrict__ Kw, short* __restrict__ Vw, int M, int N, int K)
{
    __shared__ alignas(16) short LB[2][128 * 64 + BN * 64];
    short* Ct = &LB[0][0];           // SPLIT3 epilogue: [128][128] (exactly 32KB)

    const int tid = threadIdx.x, w = tid >> 6, lane = tid & 63;
    const int quad = lane >> 4, l16 = lane & 15;
    constexpr int MT = (BN == 128) ? 4 : 2;
    const int wm = (BN == 128) ? (w >> 1) : w;
    const int wn = (BN == 128) ? (w & 1) : 0;
    const int m0 = blockIdx.y * 128, n0 = blockIdx.x * BN;
    // staging: one gload16 = 64 lanes x 16B = 8 rows x 128B
    const int srow = lane >> 3;                 // 0..7 within the 8-row chunk
    const int scol = ((lane & 7) ^ srow) * 8;   // pre-swizzled source chunk

    f32x4 acc[MT][4] = {};

    // issue all staging loads for K-tile k0s into LB[buf]
    #define STAGE_G(k0s, buf)                                                               \
        do {                                                                                \
            short* As_ = &LB[buf][0];                                                       \
            short* Bs_ = &LB[buf][128 * 64];                                                \
            _Pragma("unroll")                                                               \
            for (int jj = 0; jj < 4; ++jj) {                                                \
                const int rb = w * 32 + jj * 8;                                             \
                GLOAD_LDS16(&A[(size_t)(m0 + rb + srow) * K + (k0s) + scol], &As_[rb * 64]);\
            }                                                                               \
            if (BN == 128) {                                                                \
                _Pragma("unroll")                                                           \
                for (int jj = 0; jj < 4; ++jj) {                                            \
                    const int rb = w * 32 + jj * 8;                                         \
                    GLOAD_LDS16(&Bt[(size_t)(n0 + rb + srow) * K + (k0s) + scol],           \
                                &Bs_[rb * 64]);                                             \
                }                                                                           \
            } else {                                                                        \
                _Pragma("unroll")                                                           \
                for (int jj = 0; jj < 2; ++jj) {                                            \
                    const int rb = w * 16 + jj * 8;                                         \
                    GLOAD_LDS16(&Bt[(size_t)(n0 + rb + srow) * K + (k0s) + scol],           \
                                &Bs_[rb * 64]);                                             \
                }                                                                           \
            }                                                                               \
        } while (0)

    STAGE_G(0, 0);

    int cur = 0;
    for (int k0 = 0; k0 < K; k0 += 64) {
        // ---- issue next tile's loads into the other buffer ----
        const int kn = (k0 + 64 < K) ? k0 + 64 : k0;   // clamp: uniform issue count
        STAGE_G(kn, cur ^ 1);

        // ---- counted drain: batch(t) landed, batch(t+1) stays in flight ----
        if (BN == 128) asm volatile("s_waitcnt vmcnt(8)" ::: "memory");
        else           asm volatile("s_waitcnt vmcnt(6)" ::: "memory");
        __builtin_amdgcn_s_barrier();
        __builtin_amdgcn_sched_barrier(0);

        // ---- compute current buffer ----
        const short* As = &LB[cur][0];
        const short* Bs = &LB[cur][128 * 64];
        #pragma unroll
        for (int half = 0; half < 2; ++half) {
            const int kc2 = half * 4 + quad;    // 16B chunk index 0..7
            bf16x8 af[MT], bfr[4];
            #pragma unroll
            for (int i = 0; i < MT; ++i) {
                const int row = wm * (MT * 16) + i * 16 + l16;
                af[i] = *(const bf16x8*)&As[row * 64 + ((kc2 ^ (row & 7)) << 3)];
            }
            #pragma unroll
            for (int i = 0; i < 4; ++i) {
                const int row = wn * 64 + i * 16 + l16;
                bfr[i] = *(const bf16x8*)&Bs[row * 64 + ((kc2 ^ (row & 7)) << 3)];
            }
            __builtin_amdgcn_s_setprio(1);
            #pragma unroll
            for (int mt = 0; mt < MT; ++mt)
                #pragma unroll
                for (int nt = 0; nt < 4; ++nt)
                    acc[mt][nt] = MFMA16(af[mt], bfr[nt], acc[mt][nt]);
            __builtin_amdgcn_s_setprio(0);
        }

        // ---- exit barrier: reads of buf[cur] complete before t+1 writes it ----
        __builtin_amdgcn_s_barrier();
        cur ^= 1;
    }
    #undef STAGE_G

    // drain the redundant in-flight batch (targets buf0 == Ct) before reuse
    asm volatile("s_waitcnt vmcnt(0)" ::: "memory");
    __builtin_amdgcn_s_barrier();

    if (SPLIT3) {
        const int g = n0 >> 10;                     // 0=q,1=k,2=v (block-uniform)
        const int lc0 = n0 & 1023;
        // ---- stage 128x128 C tile into LDS, 16B-chunk XOR swizzle ----
        if (g < 2) {
            // row-major: Ct[row][((col>>3) ^ (row&15))*8 + (col&7)]
            #pragma unroll
            for (int nt = 0; nt < 4; ++nt) {
                const int col = wn * 64 + nt * 16 + l16;
                const float bv = bf2f(bias[n0 + col]);
                const int chunk = col >> 3, wi = col & 7;
                #pragma unroll
                for (int mt = 0; mt < 4; ++mt) {
                    const int rbase = wm * 64 + mt * 16 + quad * 4;
                    #pragma unroll
                    for (int r = 0; r < 4; ++r) {
                        const int row = rbase + r;
                        float v = acc[mt][nt][r] + bv;
                        if (g == 0) v *= QK_SCALE;
                        Ct[row * 128 + (((chunk ^ (row & 15)) << 3) | wi)] = f2bf(v);
                    }
                }
            }
        } else {
            // transposed [d][key]: Ct[d][((key>>3) ^ (d&15))*8 + (key&7)],
            // 4 contiguous keys per acc reg quad -> one 8B store
            #pragma unroll
            for (int nt = 0; nt < 4; ++nt) {
                const int d = wn * 64 + nt * 16 + l16;
                const float bv = bf2f(bias[n0 + d]);
                const int dsw = d & 15;
                #pragma unroll
                for (int mt = 0; mt < 4; ++mt) {
                    const int key0 = wm * 64 + mt * 16 + quad * 4;
                    bf16x4 p = {f2bf(acc[mt][nt][0] + bv), f2bf(acc[mt][nt][1] + bv),
                                f2bf(acc[mt][nt][2] + bv), f2bf(acc[mt][nt][3] + bv)};
                    *(bf16x4*)&Ct[d * 128 + ((((key0 >> 3) ^ dsw) << 3) | (key0 & 7))] = p;
                }
            }
        }
        __syncthreads();
        // ---- coalesced writeout ----
        const int batch = m0 >> 11;
        const int kc0 = (m0 & 2047) >> 6;           // even; tile covers kc0, kc0+1
        const int head0 = lc0 >> 6;                 // even; tile covers head0, head0+1
        if (g == 0) {
            short* dst = (short*)C;                 // Qw, row-major [4096][1024]
            #pragma unroll
            for (int i = 0; i < 8; ++i) {
                const int idx = i * 256 + tid;      // 0..2047
                const int row = idx >> 4, chunk = idx & 15;
                bf16x8 v = *(const bf16x8*)&Ct[row * 128 + ((chunk ^ (row & 15)) << 3)];
                *(bf16x8*)&dst[(size_t)(m0 + row) * 1024 + lc0 + chunk * 8] = v;
            }
        } else if (g == 1) {
            // Kx[bh][kc][c=(s*2+h2)*64+lane][j] = K[kc*64+s*16+l16][h2*32+quad*8+j]
            #pragma unroll
            for (int i = 0; i < 8; ++i) {
                const int idx = i * 256 + tid;
                const int qd = idx >> 9, c = idx & 511;
                const int kcL = qd >> 1, headL = qd & 1;
                const int s = c >> 7, h2 = (c >> 6) & 1;
                const int l16c = c & 15, quadc = (c >> 4) & 3;
                const int row = kcL * 64 + s * 16 + l16c;
                const int colc = headL * 8 + h2 * 4 + quadc;
                bf16x8 v = *(const bf16x8*)&Ct[row * 128 + ((colc ^ (row & 15)) << 3)];
                const int bh = batch * 16 + head0 + headL, kc = kc0 + kcL;
                *(bf16x8*)&Kw[((size_t)(bh * 32 + kc) * 512 + c) * 8] = v;
            }
        } else {
            // Vx[bh][kc][c=(h2*4+dt)*64+lane][j] = V[key][dt*16+l16] with the
            // PERMUTED key = kcL*64 + h2*32 + (j>>2)*16 + quadc*4 + (j&3):
            // j=0..3 -> keys Ka..Ka+3, j=4..7 -> keys Ka+16..Ka+19.
            #pragma unroll
            for (int i = 0; i < 8; ++i) {
                const int idx = i * 256 + tid;
                const int qd = idx >> 9, c = idx & 511;
                const int kcL = qd >> 1, headL = qd & 1;
                const int h2 = c >> 8, dt = (c >> 6) & 3;
                const int l16c = c & 15, quadc = (c >> 4) & 3;
                const int d = headL * 64 + dt * 16 + l16c;
                const int Ka = kcL * 64 + h2 * 32 + quadc * 4;
                const int Kb = Ka + 16;
                bf16x4 va = *(const bf16x4*)&Ct[d * 128 + (((Ka >> 3) ^ (d & 15)) << 3) + (Ka & 7)];
                bf16x4 vb = *(const bf16x4*)&Ct[d * 128 + (((Kb >> 3) ^ (d & 15)) << 3) + (Kb & 7)];
                bf16x8 v = {va[0], va[1], va[2], va[3], vb[0], vb[1], vb[2], vb[3]};
                const int bh = batch * 16 + head0 + headL, kc = kc0 + kcL;
                *(bf16x8*)&Vw[((size_t)(bh * 32 + kc) * 512 + c) * 8] = v;
            }
        }
    } else {
        #pragma unroll
        for (int nt = 0; nt < 4; ++nt) {
            const int col = n0 + wn * 64 + nt * 16 + l16;
            const float bv = bf2f(bias[col]);
            #pragma unroll
            for (int mt = 0; mt < MT; ++mt) {
                const int row = m0 + wm * (MT * 16) + mt * 16 + quad * 4;
                #pragma unroll
                for (int r = 0; r < 4; ++r) {
                    float v = acc[mt][nt][r] + bv;
                    if (F32OUT) ((float*)C)[(size_t)(row + r) * N + col] = v;
                    else        ((short*)C)[(size_t)(row + r) * N + col] = f2bf(v);
                }
            }
        }
    }
}

// ---------- causal flash attention: 64-row q-bands, occupancy-first ----------
// One block = one 64-row band (4 waves x 16 rows), keys kc=0..n: every wave
// active every step, uniform trip count. Ps unioned into KV -> 48KB -> 3
// blocks/CU. Grid 1024 blocks, longest-band-first. Counted-vmcnt triple-buffer
// staging pipeline (T3/T4). P never touches LDS: QK accumulator consumed
// directly as PV B-operand via the key-permuted Vx layout. T5 setprio wraps
// the MFMA clusters.
__global__ __launch_bounds__(256) void attn_kernel(
    const short* __restrict__ Qw, const short* __restrict__ Kx,
    const short* __restrict__ Vx, short* __restrict__ comb)
{
    __shared__ alignas(16) short KV[3][2][4096];      // 48KB; reused as Ps post-loop

    const int tid = threadIdx.x, w4 = tid >> 6, lane = tid & 63;
    const int quad = lane >> 4, l16 = lane & 15;
    const int blk = blockIdx.x;
    const int n = 31 - (blk >> 5);                  // band index, longest first
    const int bh = blk & 31;
    const int batch = bh >> 4, head = bh & 15;
    const size_t rowbase = (size_t)batch * 2048;
    const int hcol = head * 64;
    const int q0 = n * 64 + w4 * 16;                // this wave's 16 q-rows
    const short* Kxbh = Kx + (size_t)bh * 131072;
    const short* Vxbh = Vx + (size_t)bh * 131072;
    const int lofs = lane * 8;

    // Q fragment (B-operand: q = l16, d = quad*8+j (+32))
    bf16x8 qf[2];
    {
        const short* pq = &Qw[(rowbase + q0 + l16) * 1024 + hcol];
        qf[0] = *(const bf16x8*)(pq + quad * 8);
        qf[1] = *(const bf16x8*)(pq + 32 + quad * 8);
    }
    // drain Q loads so in-loop vmcnt counts are statically exact
    asm volatile("s_waitcnt vmcnt(0)" ::: "memory");

    f32x4 ot[4] = {};
    float lacc = 0.f;

    // per-wave staging slice: wave w4 stages chunks {j*256 + w4*64 + lane}
    const int sbase = w4 * 64;

    #define STAGE_KV(kcs, buf)                                                              \
        do {                                                                                \
            const size_t nb_ = (size_t)(kcs)*4096;                                          \
            _Pragma("unroll")                                                               \
            for (int j = 0; j < 2; ++j) {                                                   \
                GLOAD_LDS16(&Kxbh[nb_ + (size_t)(j * 256 + sbase + lane) * 8],              \
                            &KV[buf][0][(j * 256 + sbase) * 8]);                            \
                GLOAD_LDS16(&Vxbh[nb_ + (size_t)(j * 256 + sbase + lane) * 8],              \
                            &KV[buf][1][(j * 256 + sbase) * 8]);                            \
            }                                                                               \
        } while (0)

    // prologue: stage kc=0 -> buf0, kc=min(1,n) -> buf1
    STAGE_KV(0, 0);
    STAGE_KV((n >= 1) ? 1 : 0, 1);
    asm volatile("s_waitcnt vmcnt(4)" ::: "memory");   // drain batch(0), keep batch(1)
    __builtin_amdgcn_s_barrier();
    __builtin_amdgcn_sched_barrier(0);

    int cur = 0;
    for (int kc = 0; kc <= n; ++kc) {
        // ---- issue batch(kc+2) into buf (kc+2)%3 (clamped: uniform 4 loads/step) ----
        {
            const int ks = (kc + 2 <= n) ? kc + 2 : n;
            const int wb = (cur + 2 >= 3) ? cur - 1 : cur + 2;
            STAGE_KV(ks, wb);
        }

        // ---- K fragments from LDS ----
        bf16x8 kf[4][2];
        #pragma unroll
        for (int s = 0; s < 4; ++s) {
            kf[s][0] = *(const bf16x8*)&KV[cur][0][(s * 2 + 0) * 512 + lofs];
            kf[s][1] = *(const bf16x8*)&KV[cur][0][(s * 2 + 1) * 512 + lofs];
        }

        // ---- QK (S^T = K.Q^T) ----
        f32x4 sv[4];
        __builtin_amdgcn_s_setprio(1);
        #pragma unroll
        for (int s = 0; s < 4; ++s) {
            f32x4 a = {0.f, 0.f, 0.f, 0.f};
            a = MFMA16(kf[s][0], qf[0], a);
            a = MFMA16(kf[s][1], qf[1], a);
            sv[s] = a;
        }
        __builtin_amdgcn_s_setprio(0);

        // ---- V fragments from LDS (key-permuted layout) ----
        bf16x8 vf[2][4];
        #pragma unroll
        for (int hh = 0; hh < 2; ++hh)
            #pragma unroll
            for (int dt = 0; dt < 4; ++dt)
                vf[hh][dt] = *(const bf16x8*)&KV[cur][1][(hh * 4 + dt) * 512 + lofs];

        // ---- mask (last step only) -> exp2 -> pack in-register -> PV ----
        if (kc == n) {
            const int qq = q0 + l16;
            #pragma unroll
            for (int s = 0; s < 4; ++s) {
                const int keyb = kc * 64 + s * 16 + quad * 4;
                #pragma unroll
                for (int r = 0; r < 4; ++r)
                    sv[s][r] = (keyb + r <= qq) ? sv[s][r] : -1e30f;
            }
        }
        {
            unsigned u[4][2];
            #pragma unroll
            for (int s = 0; s < 4; ++s) {
                #pragma unroll
                for (int r = 0; r < 4; ++r) sv[s][r] = exp2f(sv[s][r]);
                lacc += (sv[s][0] + sv[s][1]) + (sv[s][2] + sv[s][3]);
                u[s][0] = pk_bf16(sv[s][0], sv[s][1]);
                u[s][1] = pk_bf16(sv[s][2], sv[s][3]);
            }
            bf16x8 pf0, pf1;
            {
                unsigned t0[4] = {u[0][0], u[0][1], u[1][0], u[1][1]};
                unsigned t1[4] = {u[2][0], u[2][1], u[3][0], u[3][1]};
                __builtin_memcpy(&pf0, t0, 16);
                __builtin_memcpy(&pf1, t1, 16);
            }
            __builtin_amdgcn_s_setprio(1);
            #pragma unroll
            for (int dt = 0; dt < 4; ++dt) {
                ot[dt] = MFMA16(vf[0][dt], pf0, ot[dt]);
                ot[dt] = MFMA16(vf[1][dt], pf1, ot[dt]);
            }
            __builtin_amdgcn_s_setprio(0);
        }

        // ---- counted-vmcnt sync: drain batch(kc+1), keep batch(kc+2) in flight ----
        asm volatile("s_waitcnt vmcnt(4)" ::: "memory");
        __builtin_amdgcn_s_barrier();
        __builtin_amdgcn_sched_barrier(0);
        cur = (cur + 1 >= 3) ? 0 : cur + 1;
    }
    #undef STAGE_KV

    // ---- drain all in-flight staging before reusing KV as the Ps buffer ----
    asm volatile("s_waitcnt vmcnt(0)" ::: "memory");
    __builtin_amdgcn_s_barrier();

    // ---- l reduction (lanes sharing l16 across quads) + epilogue ----
    lacc += __shfl_xor(lacc, 16);
    lacc += __shfl_xor(lacc, 32);
    const float inv = 1.0f / lacc;

    short* pw = &KV[0][0][0] + w4 * 1152;   // per-wave 16x72 transpose buffer
    #pragma unroll
    for (int dt = 0; dt < 4; ++dt) {
        *(unsigned*)&pw[l16 * 72 + dt * 16 + quad * 4]     = pk_bf16(ot[dt][0] * inv, ot[dt][1] * inv);
        *(unsigned*)&pw[l16 * 72 + dt * 16 + quad * 4 + 2] = pk_bf16(ot[dt][2] * inv, ot[dt][3] * inv);
    }
    {
        const int qr = lane >> 2, dc = (lane & 3) * 16;
        bf16x8 a0 = *(const bf16x8*)&pw[qr * 72 + dc];
        bf16x8 a1 = *(const bf16x8*)&pw[qr * 72 + dc + 8];
        short* dst = &comb[(rowbase + q0 + qr) * 1024 + hcol + dc];
        *(bf16x8*)dst = a0;
        *(bf16x8*)(dst + 8) = a1;
    }
}

// ---------- launch ----------
extern "C" void kernel_launch(void* const* d_in, const int* in_sizes, int n_in,
                              void* d_out, int out_size, void* d_ws, size_t ws_size,
                              hipStream_t stream)
{
    const float* enc = (const float*)d_in[0];
    const float* Wa  = (const float*)d_in[1];
    const float* ba  = (const float*)d_in[2];
    const float* Wo  = (const float*)d_in[3];
    const float* bo  = (const float*)d_in[4];
    float* out = (float*)d_out;

    // layout (41 MB peak):
    // [0,8)   Abf (dead after gemm1) -> comb
    // [8,10)  WtO    [10,11) biases
    // [11,17) WtA    [17,25) Kx    [25,33) Vx    [33,41) Qw
    char* ws = (char*)d_ws;
    short* Abf  = (short*)ws;
    short* comb = (short*)ws;
    short* WtO  = (short*)(ws + ((size_t)8 << 20));
    short* bbA  = (short*)(ws + ((size_t)10 << 20));
    short* bbO  = (short*)(ws + ((size_t)10 << 20) + 16384);
    short* WtA  = (short*)(ws + ((size_t)11 << 20));
    short* Kx   = (short*)(ws + ((size_t)17 << 20));
    short* Vx   = (short*)(ws + ((size_t)25 << 20));
    short* Qw   = (short*)(ws + ((size_t)33 << 20));

    prep_kernel<<<3074, 256, 0, stream>>>(enc, Wa, ba, Wo, bo, Abf, WtA, bbA, WtO, bbO);
    gemm_bt<128, false, true><<<dim3(24, 32), 256, 0, stream>>>(
        Abf, WtA, bbA, Qw, Kx, Vx, 4096, 3072, 1024);
    attn_kernel<<<1024, 256, 0, stream>>>(Qw, Kx, Vx, comb);
    gemm_bt<128, true, false><<<dim3(8, 32), 256, 0, stream>>>(
        comb, WtO, bbO, out, nullptr, nullptr, 4096, 1024, 1024);
}